// Round 9
// baseline (148.667 us; speedup 1.0000x reference)
//
#include <hip/hip_runtime.h>
#include <cstdint>
#include <cstddef>

#define BB 4
#define NN 32768
#define PRE 4096
#define POST 512
#define NW 64        // u64 words per full mask row = PRE/64
#define PSEL 1024    // prefix selection size (hot path)
#define PREF_CH 16   // PSEL/64 chunks
#define NBIN 4096    // 12-bit bins (enc >> 20)
#define CEQ 32768    // eq-bin candidate capacity (cannot overflow)

typedef unsigned long long u64;
typedef unsigned int u32;

// LDS bank-conflict swizzle for the fallback's u64 sort buffer
#define SW(i) ((i) ^ (((i) >> 4) & 15))

__device__ __forceinline__ u32 enc_f32(float f) {
  u32 u = __float_as_uint(f);
  u32 m = (u32)((int)u >> 31) | 0x80000000u;  // neg -> 0xFFFFFFFF, pos -> 0x80000000
  return u ^ m;                                // ascending u <=> ascending f
}

// ======== kernel 1: scores/labels from cls + per-block 4096-bin hist ========
// grid (16, BB) x 256 thr; 8 boxes/thread. bhist[(b*16+blk)][NBIN] needs no
// zeroing (each block fully writes its own row from a zeroed LDS hist).
__global__ __launch_bounds__(256) void prep_kernel(
    const float* __restrict__ cls, float* __restrict__ scores,
    int* __restrict__ labels, u32* __restrict__ bhist) {
  int blk = blockIdx.x, b = blockIdx.y;
  int tid = threadIdx.x;
  __shared__ u32 lhist[NBIN];
  for (int i = tid; i < NBIN; i += 256) lhist[i] = 0;
  __syncthreads();

  const int E = blk * 2048 + tid * 8;  // batch-relative element
  const float4* cp4 = (const float4*)(cls + ((size_t)b * NN + E) * 3);
  float4 v0 = cp4[0], v1 = cp4[1], v2 = cp4[2], v3 = cp4[3], v4 = cp4[4], v5 = cp4[5];
  float fa[24] = {v0.x, v0.y, v0.z, v0.w, v1.x, v1.y, v1.z, v1.w,
                  v2.x, v2.y, v2.z, v2.w, v3.x, v3.y, v3.z, v3.w,
                  v4.x, v4.y, v4.z, v4.w, v5.x, v5.y, v5.z, v5.w};
  float sc8[8];
  int lb8[8];
#pragma unroll
  for (int k = 0; k < 8; ++k) {
    float c0 = fa[3 * k], c1 = fa[3 * k + 1], c2 = fa[3 * k + 2];
    float m = c0; int l = 0;
    if (c1 > m) { m = c1; l = 1; }
    if (c2 > m) { m = c2; l = 2; }
    sc8[k] = m;
    lb8[k] = l;
    atomicAdd(&lhist[enc_f32(m) >> 20], 1u);
  }
  float4* so = (float4*)(scores + (size_t)b * NN + E);
  so[0] = make_float4(sc8[0], sc8[1], sc8[2], sc8[3]);
  so[1] = make_float4(sc8[4], sc8[5], sc8[6], sc8[7]);
  int4* lo = (int4*)(labels + (size_t)b * NN + E);
  lo[0] = make_int4(lb8[0], lb8[1], lb8[2], lb8[3]);
  lo[1] = make_int4(lb8[4], lb8[5], lb8[6], lb8[7]);
  __syncthreads();
  u32* row = bhist + (size_t)(b * 16 + blk) * NBIN;
  for (int i = tid; i < NBIN; i += 256) row[i] = lhist[i];
}

// ======== kernel 2: pivot bin per batch (grid BB x 256) =====================
// pb = bin with count(bin>pb) < PSEL <= count(bin>=pb); st2 = {pb, need}.
// Also zeroes gcnt for compact.
__global__ __launch_bounds__(256) void pivot_kernel(
    const u32* __restrict__ bhist, int* __restrict__ st2, u32* __restrict__ gcnt) {
  int b = blockIdx.x, t = threadIdx.x;
  u32 sb[16];
#pragma unroll
  for (int j = 0; j < 16; ++j) {
    u32 s = 0;
#pragma unroll
    for (int k = 0; k < 16; ++k) s += bhist[(size_t)(b * 16 + k) * NBIN + t * 16 + j];
    sb[j] = s;
  }
  u32 T = 0;
#pragma unroll
  for (int j = 0; j < 16; ++j) T += sb[j];
  __shared__ u32 ssum[256];
  ssum[t] = T;
  __syncthreads();
  for (int off = 1; off < 256; off <<= 1) {
    u32 v = ssum[t];
    u32 a = (t + off < 256) ? ssum[t + off] : 0u;
    __syncthreads();
    ssum[t] = v + a;
    __syncthreads();
  }
  u32 cum = (t < 255) ? ssum[t + 1] : 0u;  // all bins beyond my range
  for (int j = 15; j >= 0; --j) {
    u32 incl = cum + sb[j];
    if (incl >= (u32)PSEL && cum < (u32)PSEL) {  // unique crossing
      st2[b * 2 + 0] = t * 16 + j;
      st2[b * 2 + 1] = PSEL - (int)cum;  // need from pivot bin
    }
    cum = incl;
  }
  if (t == 0) { gcnt[b * 2 + 0] = 0; gcnt[b * 2 + 1] = 0; }
}

// ======== kernel 3: compact candidates (grid (16,BB) x 256) =================
// bin > pb -> cand[b][.] (guaranteed < PSEL entries); bin == pb -> ceq[b][.].
// Wave-aggregated global atomics (2 per wave).
__global__ __launch_bounds__(256) void compact_kernel(
    const float* __restrict__ scores, const int* __restrict__ st2,
    u32* __restrict__ gcnt, u64* __restrict__ cand, u64* __restrict__ ceq) {
  int blk = blockIdx.x, b = blockIdx.y;
  int tid = threadIdx.x, lane = tid & 63;
  const int E = blk * 2048 + tid * 8;
  const float4* s4 = (const float4*)(scores + (size_t)b * NN + E);
  float4 a = s4[0], c = s4[1];
  float fs[8] = {a.x, a.y, a.z, a.w, c.x, c.y, c.z, c.w};
  const u32 pb = (u32)st2[b * 2 + 0];
  u32 encs[8];
  u32 gbits = 0, ebits = 0;
  u32 gtl = 0, eql = 0;
#pragma unroll
  for (int k = 0; k < 8; ++k) {
    u32 u = enc_f32(fs[k]);
    encs[k] = u;
    u32 bin = u >> 20;
    if (bin > pb) { gbits |= 1u << k; gtl++; }
    else if (bin == pb) { ebits |= 1u << k; eql++; }
  }
  u64 pack = ((u64)gtl << 32) | eql;
#pragma unroll
  for (int off = 1; off < 64; off <<= 1) {
    u64 t = __shfl_up(pack, off, 64);
    if (lane >= off) pack += t;
  }
  u64 tot = __shfl(pack, 63, 64);
  u32 bg = 0, be = 0;
  if (lane == 63) {
    bg = atomicAdd(&gcnt[b * 2 + 0], (u32)(tot >> 32));
    be = atomicAdd(&gcnt[b * 2 + 1], (u32)(tot & 0xFFFFFFFFu));
  }
  bg = (u32)__shfl((int)bg, 63, 64);
  be = (u32)__shfl((int)be, 63, 64);
  int pg = (int)(bg + (u32)(pack >> 32) - gtl);
  int pe = (int)(be + (u32)(pack & 0xFFFFFFFFu) - eql);
#pragma unroll
  for (int k = 0; k < 8; ++k) {
    u64 key = ((u64)encs[k] << 32) | (u32)(~(u32)(E + k));
    if ((gbits >> k) & 1u) cand[(size_t)b * PSEL + (pg++)] = key;
    else if ((ebits >> k) & 1u) ceq[(size_t)b * CEQ + (pe++)] = key;
  }
}

// ======== kernel 4: rank-select eq + hybrid bitonic sort (grid BB x 1024) ===
__global__ __launch_bounds__(1024) void sort1024_kernel(
    const float* __restrict__ scores, const float* __restrict__ boxes,
    const int* __restrict__ st2, const u32* __restrict__ gcnt,
    const u64* __restrict__ cand, const u64* __restrict__ ceq,
    int* __restrict__ top_idx, float* __restrict__ top_score,
    float* __restrict__ bx1, float* __restrict__ bx2,
    float* __restrict__ by1, float* __restrict__ by2, float* __restrict__ bar) {
  int b = blockIdx.x;
  int tid = threadIdx.x;
  const float* sc = scores + (size_t)b * NN;
  __shared__ u64 sortbuf[PSEL];
  __shared__ u64 ebuf[2048];

  const int g = (int)gcnt[b * 2 + 0];      // count in bins > pb ( < PSEL )
  const int m = (int)gcnt[b * 2 + 1];      // count in pivot bin ( >= need )
  const int need = st2[b * 2 + 1];         // g + need == PSEL

  if (tid < g) sortbuf[tid] = cand[(size_t)b * PSEL + tid];

  // rank-select: key's rank among ceq (# greater) is its output slot
  const int qmax = (m + 1023) >> 10;
  for (int q = 0; q < qmax; ++q) {
    int i = q * 1024 + tid;
    u64 kk = (i < m) ? ceq[(size_t)b * CEQ + i] : 0ull;
    u32 rr = 0;
    for (int base = 0; base < m; base += 2048) {
      int cn = min(2048, m - base);
      __syncthreads();
      for (int k = tid; k < cn; k += 1024) ebuf[k] = ceq[(size_t)b * CEQ + base + k];
      __syncthreads();
      for (int j = 0; j < cn; ++j) rr += (ebuf[j] > kk);
    }
    if (i < m && rr < (u32)need) sortbuf[g + rr] = kk;  // ranks 0..need-1 unique
  }
  __syncthreads();

  // --- hybrid bitonic sort, 1 elem/thread: shfl j<64, LDS j>=64 (round 7) ---
  u64 key = sortbuf[tid];
#pragma unroll
  for (int k2 = 2; k2 <= 64; k2 <<= 1) {
    for (int j = k2 >> 1; j > 0; j >>= 1) {
      u64 o = __shfl_xor(key, j, 64);
      bool take_max = (((tid & k2) == 0) == ((tid & j) == 0));
      key = ((key > o) == take_max) ? key : o;
    }
  }
  for (int k2 = 128; k2 <= PSEL; k2 <<= 1) {
    for (int j = k2 >> 1; j >= 64; j >>= 1) {
      __syncthreads();
      sortbuf[tid] = key;
      __syncthreads();
      u64 o = sortbuf[tid ^ j];
      bool take_max = (((tid & k2) == 0) == ((tid & j) == 0));
      key = ((key > o) == take_max) ? key : o;
    }
    for (int j = 32; j > 0; j >>= 1) {
      u64 o = __shfl_xor(key, j, 64);
      bool take_max = (((tid & k2) == 0) == ((tid & j) == 0));
      key = ((key > o) == take_max) ? key : o;
    }
  }

  // --- epilogue: one sorted element per thread (round 7) ---
  {
#pragma clang fp contract(off)
    int e = (int)(~(u32)(key & 0xFFFFFFFFull));
    top_idx[b * PRE + tid] = e;
    top_score[b * PRE + tid] = sc[e];
    const float* bx = boxes + ((size_t)b * NN + e) * 7;
    float x = bx[0], y = bx[1], dx = bx[3], dy = bx[4];
    float hx = dx * 0.5f, hy = dy * 0.5f;
    bx1[b * PRE + tid] = x - hx;
    bx2[b * PRE + tid] = x + hx;
    by1[b * PRE + tid] = y - hy;
    by2[b * PRE + tid] = y + hy;
    bar[b * PRE + tid] = dx * dy;
  }
}

// ======== cold fallback: round-4 top-PRE select (gated) =====================
template<int SELN, bool GATED>
__global__ __launch_bounds__(1024) void select_kernel_t(
    const float* __restrict__ scores, const float* __restrict__ boxes,
    const int* __restrict__ st_info,
    int* __restrict__ top_idx, float* __restrict__ top_score,
    float* __restrict__ bx1, float* __restrict__ bx2,
    float* __restrict__ by1, float* __restrict__ by2, float* __restrict__ bar) {
  int b = blockIdx.x;
  if (GATED && st_info[b * 2 + 0] >= POST) return;  // fallback not needed
  int tid = threadIdx.x;
  int wv = tid >> 6;
  const float* sc = scores + (size_t)b * NN;

  __shared__ u32 hist16[16][256];   // per-wave privatized histograms
  __shared__ u32 sA[256], sB[256];  // suffix-scan ping-pong
  __shared__ u32 scanbuf[1024];
  __shared__ u64 sortbuf[SELN];
  __shared__ u32 sh_prefix;
  __shared__ int sh_rem;

  const int e0 = tid * 32;
  u32 encs[32];
  {
    const float4* sc4 = (const float4*)(sc + e0);
#pragma unroll
    for (int k = 0; k < 8; ++k) {
      float4 v = sc4[k];
      encs[k * 4 + 0] = enc_f32(v.x);
      encs[k * 4 + 1] = enc_f32(v.y);
      encs[k * 4 + 2] = enc_f32(v.z);
      encs[k * 4 + 3] = enc_f32(v.w);
    }
  }

  u32 prefix = 0, known = 0;
  int remaining = SELN;
  for (int shift = 24; shift >= 0; shift -= 8) {
    for (int k = tid; k < 16 * 256; k += 1024) ((u32*)hist16)[k] = 0;
    __syncthreads();
#pragma unroll
    for (int k = 0; k < 32; ++k) {
      u32 u = encs[k];
      if ((u & known) == prefix) atomicAdd(&hist16[wv][(u >> shift) & 255u], 1u);
    }
    __syncthreads();
    if (tid < 256) {
      u32 t = 0;
#pragma unroll
      for (int w2 = 0; w2 < 16; ++w2) t += hist16[w2][tid];
      sA[tid] = t;
    }
    __syncthreads();
    u32* src = sA; u32* dst = sB;
    for (int off = 1; off < 256; off <<= 1) {
      if (tid < 256) dst[tid] = src[tid] + ((tid + off < 256) ? src[tid + off] : 0u);
      __syncthreads();
      u32* tp = src; src = dst; dst = tp;
    }
    if (tid < 256) {
      u32 sv = src[tid];
      u32 svn = (tid < 255) ? src[tid + 1] : 0u;
      if (sv >= (u32)remaining && svn < (u32)remaining) {
        sh_prefix = prefix | ((u32)tid << shift);
        sh_rem = remaining - (int)svn;
      }
    }
    __syncthreads();
    prefix = sh_prefix;
    remaining = sh_rem;
    known |= (0xFFu << shift);
    __syncthreads();
  }
  const u32 pivot = prefix;

  int gtc = 0, eqc = 0;
#pragma unroll
  for (int k = 0; k < 32; ++k) {
    gtc += (encs[k] > pivot);
    eqc += (encs[k] == pivot);
  }
  scanbuf[tid] = ((u32)gtc << 16) | (u32)eqc;
  __syncthreads();
  for (int off = 1; off < 1024; off <<= 1) {
    u32 v = scanbuf[tid];
    u32 add = (tid >= off) ? scanbuf[tid - off] : 0u;
    __syncthreads();
    scanbuf[tid] = v + add;
    __syncthreads();
  }
  u32 incl = scanbuf[tid];
  u32 totpk = scanbuf[1023];
  const int cnt_gt = (int)(totpk >> 16);
  int gt_base = (int)(incl >> 16) - gtc;
  int eq_base = (int)(incl & 0xFFFFu) - eqc;
  int gs = 0, es = 0;
#pragma unroll
  for (int k = 0; k < 32; ++k) {
    u32 u = encs[k];
    int e = e0 + k;
    u64 key = ((u64)u << 32) | (u32)(~(u32)e);
    if (u > pivot) {
      sortbuf[SW(gt_base + gs)] = key; gs++;
    } else if (u == pivot) {
      int g = eq_base + (es++);
      if (g < remaining) sortbuf[SW(cnt_gt + g)] = key;
    }
  }
  __syncthreads();

  for (int k = 2; k <= SELN; k <<= 1) {
    for (int j = k >> 1; j > 0; j >>= 1) {
      for (int p = tid; p < SELN / 2; p += 1024) {
        int low = p & (j - 1);
        int i = ((p ^ low) << 1) | low;
        int ixj = i + j;
        u64 a = sortbuf[SW(i)], c = sortbuf[SW(ixj)];
        bool desc = ((i & k) == 0);
        if (desc ? (a < c) : (a > c)) { sortbuf[SW(i)] = c; sortbuf[SW(ixj)] = a; }
      }
      __syncthreads();
    }
  }
  {
#pragma clang fp contract(off)
    for (int s = tid; s < SELN; s += 1024) {
      u64 key = sortbuf[SW(s)];
      int e = (int)(~(u32)(key & 0xFFFFFFFFull));
      top_idx[b * PRE + s] = e;
      top_score[b * PRE + s] = sc[e];
      const float* bx = boxes + ((size_t)b * NN + e) * 7;
      float x = bx[0], y = bx[1], dx = bx[3], dy = bx[4];
      float hx = dx * 0.5f, hy = dy * 0.5f;
      bx1[b * PRE + s] = x - hx;
      bx2[b * PRE + s] = x + hx;
      by1[b * PRE + s] = y - hy;
      by2[b * PRE + s] = y + hy;
      bar[b * PRE + s] = dx * dy;
    }
  }
}

// ---------------- suppression bitmask (iou > 0.7, j > i) --------------------
__device__ __forceinline__ void mask_tile(
    const float* __restrict__ bx1, const float* __restrict__ bx2,
    const float* __restrict__ by1, const float* __restrict__ by2,
    const float* __restrict__ bar, u64* __restrict__ mask,
    int b, int rb, int cb, int t) {
#pragma clang fp contract(off)
  int i = rb * 64 + t;
  int j0 = cb * 64 + t;
  float cx1 = bx1[b * PRE + j0], cx2 = bx2[b * PRE + j0];
  float cy1 = by1[b * PRE + j0], cy2 = by2[b * PRE + j0];
  float car = bar[b * PRE + j0];
  float ix1 = bx1[b * PRE + i], ix2 = bx2[b * PRE + i];
  float iy1 = by1[b * PRE + i], iy2 = by2[b * PRE + i];
  float ia = bar[b * PRE + i];
  u64 bits = 0ull;
  int jbase = cb * 64;
  for (int jj = 0; jj < 64; ++jj) {
    float jx1 = __shfl(cx1, jj, 64);
    float jx2 = __shfl(cx2, jj, 64);
    float jy1 = __shfl(cy1, jj, 64);
    float jy2 = __shfl(cy2, jj, 64);
    float jar = __shfl(car, jj, 64);
    if (jbase + jj > i) {
      float iw = fminf(ix2, jx2) - fmaxf(ix1, jx1);
      iw = fmaxf(iw, 0.0f);
      float ih = fminf(iy2, jy2) - fmaxf(iy1, jy1);
      ih = fmaxf(ih, 0.0f);
      float inter = iw * ih;
      float uni = ia + jar - inter;
      float iou = inter / fmaxf(uni, 1e-6f);
      if (iou > 0.7f) bits |= (1ull << jj);
    }
  }
  mask[((size_t)b * PRE + i) * NW + cb] = bits;
}

__global__ void mask_prefix_kernel(const float* __restrict__ bx1, const float* __restrict__ bx2,
                                   const float* __restrict__ by1, const float* __restrict__ by2,
                                   const float* __restrict__ bar, u64* __restrict__ mask) {
  int cb = blockIdx.x, rb = blockIdx.y, b = blockIdx.z;
  if (cb < rb) return;
  mask_tile(bx1, bx2, by1, by2, bar, mask, b, rb, cb, threadIdx.x);
}

__global__ __launch_bounds__(256) void mask_full_kernel(
    const float* __restrict__ bx1, const float* __restrict__ bx2,
    const float* __restrict__ by1, const float* __restrict__ by2,
    const float* __restrict__ bar, u64* __restrict__ mask,
    const int* __restrict__ st_info) {
  int b = blockIdx.z;
  if (st_info[b * 2 + 0] >= POST) return;
  int rb = blockIdx.y;
  int cb = blockIdx.x * 4 + (threadIdx.x >> 6);
  if (cb < rb) return;
  mask_tile(bx1, bx2, by1, by2, bar, mask, b, rb, cb, threadIdx.x & 63);
}

// ---------------- chunked greedy NMS, 4 waves per batch ---------------------
template<bool FULL>
__global__ __launch_bounds__(256) void nms_kernel_t(
    const u64* __restrict__ mask, u64* __restrict__ keep_words,
    int* __restrict__ st_info) {
  int b = blockIdx.x;
  if (FULL && st_info[b * 2 + 0] >= POST) return;  // hot path already done
  int tid = threadIdx.x;
  int lane = tid & 63;
  int wv = tid >> 6;
  __shared__ u64 part[2][4][64];

  const u64* base = mask + (size_t)b * PRE * NW;
  u64 rem = 0ull, keepw = 0ull;
  int kept = 0;
  const int c1 = FULL ? NW : PREF_CH;

  int c = 0;
  while (c < c1) {
    u64 remc = __shfl(rem, c, 64);
    const u64* rowp = base + ((size_t)(c * 64 + wv * 16)) * NW + lane;
    u64 m[16];
#pragma unroll
    for (int k = 0; k < 16; ++k) m[k] = rowp[(size_t)k * NW];
    u64 dg = base[((size_t)(c * 64 + lane)) * NW + c];
    u64 nz = __ballot(dg != 0ull);
    while (nz) {
      int i2 = __builtin_ctzll(nz);
      nz &= nz - 1ull;
      u64 di = __shfl(dg, i2, 64);
      if (!((remc >> i2) & 1ull)) remc |= di;
    }
    u64 K = ~remc;
    if (lane == c) keepw = K;
    kept += __popcll(K);

    u32 kb = (u32)((K >> (wv * 16)) & 0xFFFFull);
    u64 acc = 0ull;
#pragma unroll
    for (int k = 0; k < 16; ++k)
      if ((kb >> k) & 1u) acc |= m[k];
    part[c & 1][wv][lane] = acc;
    __syncthreads();
    rem |= part[c & 1][0][lane] | part[c & 1][1][lane] |
           part[c & 1][2][lane] | part[c & 1][3][lane];
    ++c;
    if (kept >= POST) break;  // uniform; later output ranks all >= POST
  }

  if (wv == 0) {
    keep_words[b * 64 + lane] = keepw;  // unprocessed chunks -> 0
    if (!FULL && lane == 0) st_info[b * 2 + 0] = kept;
  }
}

// ---------------- emit first POST kept entries ------------------------------
__global__ __launch_bounds__(1024) void output_kernel(
    const u64* __restrict__ keep_words, const int* __restrict__ top_idx,
    const float* __restrict__ top_score, const int* __restrict__ labels,
    const float* __restrict__ boxes, float* __restrict__ out) {
  int b = blockIdx.x, tid = threadIdx.x;
  __shared__ u32 scanbuf[1024];
  __shared__ int sh_total;

  u64 w = keep_words[b * 64 + (tid >> 4)];
  u32 my4 = (u32)((w >> ((tid & 15) * 4)) & 0xFull);  // 4 consecutive i per thread
  int cnt = __popc(my4);
  scanbuf[tid] = (u32)cnt;
  __syncthreads();
  for (int off = 1; off < 1024; off <<= 1) {
    u32 v = scanbuf[tid];
    u32 add = (tid >= off) ? scanbuf[tid - off] : 0u;
    __syncthreads();
    scanbuf[tid] = v + add;
    __syncthreads();
  }
  int base = (int)scanbuf[tid] - cnt;
  if (tid == 1023) sh_total = (int)scanbuf[1023];
  __syncthreads();
  int total = sh_total;

  float* rois = out;                 // BB*POST*7
  float* rsc = out + BB * POST * 7;  // BB*POST
  float* rlb = rsc + BB * POST;      // BB*POST (labels as f32)

  int r = 0;
  for (int k = 0; k < 4; ++k) {
    if ((my4 >> k) & 1u) {
      int rank = base + (r++);
      if (rank < POST) {
        int i = tid * 4 + k;
        int idx = top_idx[b * PRE + i];
        const float* bx = boxes + ((size_t)b * NN + idx) * 7;
        float* ro = rois + ((size_t)b * POST + rank) * 7;
        for (int c = 0; c < 7; ++c) ro[c] = bx[c];
        rsc[b * POST + rank] = top_score[b * PRE + i];
        rlb[b * POST + rank] = (float)(labels[b * NN + idx] + 1);
      }
    }
  }
  // invalid slots: rois = 0, score = 0, label = 0 + 1
  for (int s = tid; s < POST; s += 1024) {
    if (s >= total) {
      float* ro = rois + ((size_t)b * POST + s) * 7;
      for (int c = 0; c < 7; ++c) ro[c] = 0.0f;
      rsc[b * POST + s] = 0.0f;
      rlb[b * POST + s] = 1.0f;
    }
  }
}

// ---------------------------------------------------------------------------
extern "C" void kernel_launch(void* const* d_in, const int* in_sizes, int n_in,
                              void* d_out, int out_size, void* d_ws, size_t ws_size,
                              hipStream_t stream) {
  const float* boxes = (const float*)d_in[0];  // (B, N, 7)
  const float* cls = (const float*)d_in[1];    // (B, N, 3)
  float* out = (float*)d_out;                  // rois | scores | labels, flat f32

  char* w = (char*)d_ws;
  float* scores = (float*)w;    w += (size_t)BB * NN * 4;
  int* labels = (int*)w;        w += (size_t)BB * NN * 4;
  int* top_idx = (int*)w;       w += (size_t)BB * PRE * 4;
  float* top_score = (float*)w; w += (size_t)BB * PRE * 4;
  float* bx1 = (float*)w;       w += (size_t)BB * PRE * 4;
  float* bx2 = (float*)w;       w += (size_t)BB * PRE * 4;
  float* by1 = (float*)w;       w += (size_t)BB * PRE * 4;
  float* by2 = (float*)w;       w += (size_t)BB * PRE * 4;
  float* bar = (float*)w;       w += (size_t)BB * PRE * 4;
  u64* mask = (u64*)w;          w += (size_t)BB * PRE * NW * 8;
  u64* keepw = (u64*)w;         w += (size_t)BB * 64 * 8;
  int* st_info = (int*)w;       w += (size_t)BB * 2 * 4;
  u32* bhist = (u32*)w;         w += (size_t)BB * 16 * NBIN * 4;
  u64* cand = (u64*)w;          w += (size_t)BB * PSEL * 8;
  u64* ceq = (u64*)w;           w += (size_t)BB * CEQ * 8;
  int* st2 = (int*)w;           w += (size_t)BB * 2 * 4;
  u32* gcnt = (u32*)w;          w += (size_t)BB * 2 * 4;

  // hot path: multi-block top-1024 selection pipeline
  prep_kernel<<<dim3(16, BB), 256, 0, stream>>>(cls, scores, labels, bhist);
  pivot_kernel<<<BB, 256, 0, stream>>>(bhist, st2, gcnt);
  compact_kernel<<<dim3(16, BB), 256, 0, stream>>>(scores, st2, gcnt, cand, ceq);
  sort1024_kernel<<<BB, 1024, 0, stream>>>(scores, boxes, st2, gcnt, cand, ceq,
                                           top_idx, top_score, bx1, bx2, by1, by2, bar);
  mask_prefix_kernel<<<dim3(PREF_CH, PREF_CH, BB), 64, 0, stream>>>(
      bx1, bx2, by1, by2, bar, mask);
  nms_kernel_t<false><<<BB, 256, 0, stream>>>(mask, keepw, st_info);
  // fallback chain (exits immediately when prefix found >= POST keepers)
  select_kernel_t<PRE, true><<<BB, 1024, 0, stream>>>(
      scores, boxes, st_info, top_idx, top_score, bx1, bx2, by1, by2, bar);
  mask_full_kernel<<<dim3(NW / 4, NW, BB), 256, 0, stream>>>(
      bx1, bx2, by1, by2, bar, mask, st_info);
  nms_kernel_t<true><<<BB, 256, 0, stream>>>(mask, keepw, st_info);
  // output
  output_kernel<<<BB, 1024, 0, stream>>>(keepw, top_idx, top_score, labels, boxes, out);
}

// Round 10
// 124.202 us; speedup vs baseline: 1.1970x; 1.1970x over previous
//
#include <hip/hip_runtime.h>
#include <cstdint>
#include <cstddef>

#define BB 4
#define NN 32768
#define PRE 4096
#define POST 512
#define NW 64        // u64 words per full mask row = PRE/64
#define PSEL 1024    // prefix selection size (hot path)
#define PREF_CH 16   // PSEL/64 chunks
#define NBIN 4096    // 12-bit bins (enc >> 20)
#define CEQ 32768    // eq-bin candidate capacity (cannot overflow)

typedef unsigned long long u64;
typedef unsigned int u32;
typedef float f4u __attribute__((ext_vector_type(4), aligned(4)));  // 4B-aligned float4

// LDS bank-conflict swizzle for the fallback's u64 sort buffer
#define SW(i) ((i) ^ (((i) >> 4) & 15))

__device__ __forceinline__ u32 enc_f32(float f) {
  u32 u = __float_as_uint(f);
  u32 m = (u32)((int)u >> 31) | 0x80000000u;  // neg -> 0xFFFFFFFF, pos -> 0x80000000
  return u ^ m;                                // ascending u <=> ascending f
}
// exact inverse of enc_f32 (bijection, bit-exact)
__device__ __forceinline__ float dec_f32(u32 e) {
  u32 u = (e & 0x80000000u) ? (e ^ 0x80000000u) : ~e;
  return __uint_as_float(u);
}

// ======== kernel 1: scores/labels from cls + per-block 4096-bin hist ========
__global__ __launch_bounds__(256) void prep_kernel(
    const float* __restrict__ cls, float* __restrict__ scores,
    int* __restrict__ labels, u32* __restrict__ bhist) {
  int blk = blockIdx.x, b = blockIdx.y;
  int tid = threadIdx.x;
  __shared__ u32 lhist[NBIN];
  for (int i = tid; i < NBIN; i += 256) lhist[i] = 0;
  __syncthreads();

  const int E = blk * 2048 + tid * 8;  // batch-relative element
  const float4* cp4 = (const float4*)(cls + ((size_t)b * NN + E) * 3);
  float4 v0 = cp4[0], v1 = cp4[1], v2 = cp4[2], v3 = cp4[3], v4 = cp4[4], v5 = cp4[5];
  float fa[24] = {v0.x, v0.y, v0.z, v0.w, v1.x, v1.y, v1.z, v1.w,
                  v2.x, v2.y, v2.z, v2.w, v3.x, v3.y, v3.z, v3.w,
                  v4.x, v4.y, v4.z, v4.w, v5.x, v5.y, v5.z, v5.w};
  float sc8[8];
  int lb8[8];
#pragma unroll
  for (int k = 0; k < 8; ++k) {
    float c0 = fa[3 * k], c1 = fa[3 * k + 1], c2 = fa[3 * k + 2];
    float m = c0; int l = 0;
    if (c1 > m) { m = c1; l = 1; }
    if (c2 > m) { m = c2; l = 2; }
    sc8[k] = m;
    lb8[k] = l;
    atomicAdd(&lhist[enc_f32(m) >> 20], 1u);
  }
  float4* so = (float4*)(scores + (size_t)b * NN + E);
  so[0] = make_float4(sc8[0], sc8[1], sc8[2], sc8[3]);
  so[1] = make_float4(sc8[4], sc8[5], sc8[6], sc8[7]);
  int4* lo = (int4*)(labels + (size_t)b * NN + E);
  lo[0] = make_int4(lb8[0], lb8[1], lb8[2], lb8[3]);
  lo[1] = make_int4(lb8[4], lb8[5], lb8[6], lb8[7]);
  __syncthreads();
  u32* row = bhist + (size_t)(b * 16 + blk) * NBIN;
  for (int i = tid; i < NBIN; i += 256) row[i] = lhist[i];
}

// ======== kernel 2: pivot bin per batch (grid BB x 256) =====================
__global__ __launch_bounds__(256) void pivot_kernel(
    const u32* __restrict__ bhist, int* __restrict__ st2, u32* __restrict__ gcnt) {
  int b = blockIdx.x, t = threadIdx.x;
  u32 sb[16];
#pragma unroll
  for (int j = 0; j < 16; ++j) {
    u32 s = 0;
#pragma unroll
    for (int k = 0; k < 16; ++k) s += bhist[(size_t)(b * 16 + k) * NBIN + t * 16 + j];
    sb[j] = s;
  }
  u32 T = 0;
#pragma unroll
  for (int j = 0; j < 16; ++j) T += sb[j];
  __shared__ u32 ssum[256];
  ssum[t] = T;
  __syncthreads();
  for (int off = 1; off < 256; off <<= 1) {
    u32 v = ssum[t];
    u32 a = (t + off < 256) ? ssum[t + off] : 0u;
    __syncthreads();
    ssum[t] = v + a;
    __syncthreads();
  }
  u32 cum = (t < 255) ? ssum[t + 1] : 0u;  // all bins beyond my range
  for (int j = 15; j >= 0; --j) {
    u32 incl = cum + sb[j];
    if (incl >= (u32)PSEL && cum < (u32)PSEL) {  // unique crossing
      st2[b * 2 + 0] = t * 16 + j;
      st2[b * 2 + 1] = PSEL - (int)cum;  // need from pivot bin
    }
    cum = incl;
  }
  if (t == 0) { gcnt[b * 2 + 0] = 0; gcnt[b * 2 + 1] = 0; }
}

// ======== kernel 3: compact candidates (grid (16,BB) x 256) =================
__global__ __launch_bounds__(256) void compact_kernel(
    const float* __restrict__ scores, const int* __restrict__ st2,
    u32* __restrict__ gcnt, u64* __restrict__ cand, u64* __restrict__ ceq) {
  int blk = blockIdx.x, b = blockIdx.y;
  int tid = threadIdx.x, lane = tid & 63;
  const int E = blk * 2048 + tid * 8;
  const float4* s4 = (const float4*)(scores + (size_t)b * NN + E);
  float4 a = s4[0], c = s4[1];
  float fs[8] = {a.x, a.y, a.z, a.w, c.x, c.y, c.z, c.w};
  const u32 pb = (u32)st2[b * 2 + 0];
  u32 encs[8];
  u32 gbits = 0, ebits = 0;
  u32 gtl = 0, eql = 0;
#pragma unroll
  for (int k = 0; k < 8; ++k) {
    u32 u = enc_f32(fs[k]);
    encs[k] = u;
    u32 bin = u >> 20;
    if (bin > pb) { gbits |= 1u << k; gtl++; }
    else if (bin == pb) { ebits |= 1u << k; eql++; }
  }
  u64 pack = ((u64)gtl << 32) | eql;
#pragma unroll
  for (int off = 1; off < 64; off <<= 1) {
    u64 t = __shfl_up(pack, off, 64);
    if (lane >= off) pack += t;
  }
  u64 tot = __shfl(pack, 63, 64);
  u32 bg = 0, be = 0;
  if (lane == 63) {
    bg = atomicAdd(&gcnt[b * 2 + 0], (u32)(tot >> 32));
    be = atomicAdd(&gcnt[b * 2 + 1], (u32)(tot & 0xFFFFFFFFu));
  }
  bg = (u32)__shfl((int)bg, 63, 64);
  be = (u32)__shfl((int)be, 63, 64);
  int pg = (int)(bg + (u32)(pack >> 32) - gtl);
  int pe = (int)(be + (u32)(pack & 0xFFFFFFFFu) - eql);
#pragma unroll
  for (int k = 0; k < 8; ++k) {
    u64 key = ((u64)encs[k] << 32) | (u32)(~(u32)(E + k));
    if ((gbits >> k) & 1u) cand[(size_t)b * PSEL + (pg++)] = key;
    else if ((ebits >> k) & 1u) ceq[(size_t)b * CEQ + (pe++)] = key;
  }
}

// ======== hybrid bitonic sort of 1024 u64, 1 elem/thread (proven r6/7/9) ====
// shfl_xor for j<64 (no LDS/barriers), LDS exchange for j>=64. Descending.
__device__ __forceinline__ u64 hybrid_sort1024(u64 key, u64* sortbuf, int tid) {
#pragma unroll
  for (int k2 = 2; k2 <= 64; k2 <<= 1) {
    for (int j = k2 >> 1; j > 0; j >>= 1) {
      u64 o = __shfl_xor(key, j, 64);
      bool take_max = (((tid & k2) == 0) == ((tid & j) == 0));
      key = ((key > o) == take_max) ? key : o;
    }
  }
  for (int k2 = 128; k2 <= PSEL; k2 <<= 1) {
    for (int j = k2 >> 1; j >= 64; j >>= 1) {
      __syncthreads();
      sortbuf[tid] = key;
      __syncthreads();
      u64 o = sortbuf[tid ^ j];
      bool take_max = (((tid & k2) == 0) == ((tid & j) == 0));
      key = ((key > o) == take_max) ? key : o;
    }
    for (int j = 32; j > 0; j >>= 1) {
      u64 o = __shfl_xor(key, j, 64);
      bool take_max = (((tid & k2) == 0) == ((tid & j) == 0));
      key = ((key > o) == take_max) ? key : o;
    }
  }
  return key;
}

// ======== kernel 4: eq-sort + final sort (grid BB x 1024) ===================
__global__ __launch_bounds__(1024) void sort1024_kernel(
    const float* __restrict__ boxes,
    const int* __restrict__ st2, const u32* __restrict__ gcnt,
    const u64* __restrict__ cand, const u64* __restrict__ ceq,
    int* __restrict__ top_idx, float* __restrict__ top_score,
    float* __restrict__ bx1, float* __restrict__ bx2,
    float* __restrict__ by1, float* __restrict__ by2, float* __restrict__ bar) {
  int b = blockIdx.x;
  int tid = threadIdx.x;
  __shared__ u64 sortbuf[PSEL];   // sort scratch
  __shared__ u64 ebuf[PSEL];      // assembled final candidate keys

  const int g = (int)gcnt[b * 2 + 0];      // count in bins > pb ( < PSEL )
  const int m = (int)gcnt[b * 2 + 1];      // count in pivot bin ( >= need )
  const int need = st2[b * 2 + 1];         // g + need == PSEL

  if (tid < g) ebuf[tid] = cand[(size_t)b * PSEL + tid];

  if (m <= PSEL) {  // common case: sort the pivot bin, take its top-need
    u64 ek = (tid < m) ? ceq[(size_t)b * CEQ + tid] : 0ull;
    ek = hybrid_sort1024(ek, sortbuf, tid);   // ek = tid-th largest eq key
    if (tid < need) ebuf[g + tid] = ek;
  } else {          // rare: rank by scan (exact for any m)
    const int qmax = (m + 1023) >> 10;
    for (int q = 0; q < qmax; ++q) {
      int i = q * 1024 + tid;
      u64 kk = (i < m) ? ceq[(size_t)b * CEQ + i] : 0ull;
      u32 rr = 0;
      for (int base = 0; base < m; base += 1024) {
        int cn = min(1024, m - base);
        __syncthreads();
        if (tid < cn) sortbuf[tid] = ceq[(size_t)b * CEQ + base + tid];
        __syncthreads();
        for (int j = 0; j < cn; ++j) rr += (sortbuf[j] > kk);
      }
      if (i < m && rr < (u32)need) ebuf[g + rr] = kk;  // ranks unique
    }
  }
  __syncthreads();

  u64 key = ebuf[tid];
  key = hybrid_sort1024(key, sortbuf, tid);

  // --- epilogue: score decoded from key; box via two 4B-aligned float4 ---
  {
#pragma clang fp contract(off)
    u32 ue = (u32)(key >> 32);
    int e = (int)(~(u32)key);
    top_idx[b * PRE + tid] = e;
    top_score[b * PRE + tid] = dec_f32(ue);
    const float* bx = boxes + ((size_t)b * NN + e) * 7;
    f4u p0 = *(const f4u*)(bx);       // x, y, z, dx
    f4u p1 = *(const f4u*)(bx + 3);   // dx, dy, dz, heading
    float x = p0.x, y = p0.y, dx = p0.w, dy = p1.y;
    float hx = dx * 0.5f, hy = dy * 0.5f;
    bx1[b * PRE + tid] = x - hx;
    bx2[b * PRE + tid] = x + hx;
    by1[b * PRE + tid] = y - hy;
    by2[b * PRE + tid] = y + hy;
    bar[b * PRE + tid] = dx * dy;
  }
}

// ======== cold fallback: round-4 top-PRE select (gated) =====================
template<int SELN, bool GATED>
__global__ __launch_bounds__(1024) void select_kernel_t(
    const float* __restrict__ scores, const float* __restrict__ boxes,
    const int* __restrict__ st_info,
    int* __restrict__ top_idx, float* __restrict__ top_score,
    float* __restrict__ bx1, float* __restrict__ bx2,
    float* __restrict__ by1, float* __restrict__ by2, float* __restrict__ bar) {
  int b = blockIdx.x;
  if (GATED && st_info[b * 2 + 0] >= POST) return;  // fallback not needed
  int tid = threadIdx.x;
  int wv = tid >> 6;
  const float* sc = scores + (size_t)b * NN;

  __shared__ u32 hist16[16][256];   // per-wave privatized histograms
  __shared__ u32 sA[256], sB[256];  // suffix-scan ping-pong
  __shared__ u32 scanbuf[1024];
  __shared__ u64 sortbuf[SELN];
  __shared__ u32 sh_prefix;
  __shared__ int sh_rem;

  const int e0 = tid * 32;
  u32 encs[32];
  {
    const float4* sc4 = (const float4*)(sc + e0);
#pragma unroll
    for (int k = 0; k < 8; ++k) {
      float4 v = sc4[k];
      encs[k * 4 + 0] = enc_f32(v.x);
      encs[k * 4 + 1] = enc_f32(v.y);
      encs[k * 4 + 2] = enc_f32(v.z);
      encs[k * 4 + 3] = enc_f32(v.w);
    }
  }

  u32 prefix = 0, known = 0;
  int remaining = SELN;
  for (int shift = 24; shift >= 0; shift -= 8) {
    for (int k = tid; k < 16 * 256; k += 1024) ((u32*)hist16)[k] = 0;
    __syncthreads();
#pragma unroll
    for (int k = 0; k < 32; ++k) {
      u32 u = encs[k];
      if ((u & known) == prefix) atomicAdd(&hist16[wv][(u >> shift) & 255u], 1u);
    }
    __syncthreads();
    if (tid < 256) {
      u32 t = 0;
#pragma unroll
      for (int w2 = 0; w2 < 16; ++w2) t += hist16[w2][tid];
      sA[tid] = t;
    }
    __syncthreads();
    u32* src = sA; u32* dst = sB;
    for (int off = 1; off < 256; off <<= 1) {
      if (tid < 256) dst[tid] = src[tid] + ((tid + off < 256) ? src[tid + off] : 0u);
      __syncthreads();
      u32* tp = src; src = dst; dst = tp;
    }
    if (tid < 256) {
      u32 sv = src[tid];
      u32 svn = (tid < 255) ? src[tid + 1] : 0u;
      if (sv >= (u32)remaining && svn < (u32)remaining) {
        sh_prefix = prefix | ((u32)tid << shift);
        sh_rem = remaining - (int)svn;
      }
    }
    __syncthreads();
    prefix = sh_prefix;
    remaining = sh_rem;
    known |= (0xFFu << shift);
    __syncthreads();
  }
  const u32 pivot = prefix;

  int gtc = 0, eqc = 0;
#pragma unroll
  for (int k = 0; k < 32; ++k) {
    gtc += (encs[k] > pivot);
    eqc += (encs[k] == pivot);
  }
  scanbuf[tid] = ((u32)gtc << 16) | (u32)eqc;
  __syncthreads();
  for (int off = 1; off < 1024; off <<= 1) {
    u32 v = scanbuf[tid];
    u32 add = (tid >= off) ? scanbuf[tid - off] : 0u;
    __syncthreads();
    scanbuf[tid] = v + add;
    __syncthreads();
  }
  u32 incl = scanbuf[tid];
  u32 totpk = scanbuf[1023];
  const int cnt_gt = (int)(totpk >> 16);
  int gt_base = (int)(incl >> 16) - gtc;
  int eq_base = (int)(incl & 0xFFFFu) - eqc;
  int gs = 0, es = 0;
#pragma unroll
  for (int k = 0; k < 32; ++k) {
    u32 u = encs[k];
    int e = e0 + k;
    u64 key = ((u64)u << 32) | (u32)(~(u32)e);
    if (u > pivot) {
      sortbuf[SW(gt_base + gs)] = key; gs++;
    } else if (u == pivot) {
      int g = eq_base + (es++);
      if (g < remaining) sortbuf[SW(cnt_gt + g)] = key;
    }
  }
  __syncthreads();

  for (int k = 2; k <= SELN; k <<= 1) {
    for (int j = k >> 1; j > 0; j >>= 1) {
      for (int p = tid; p < SELN / 2; p += 1024) {
        int low = p & (j - 1);
        int i = ((p ^ low) << 1) | low;
        int ixj = i + j;
        u64 a = sortbuf[SW(i)], c = sortbuf[SW(ixj)];
        bool desc = ((i & k) == 0);
        if (desc ? (a < c) : (a > c)) { sortbuf[SW(i)] = c; sortbuf[SW(ixj)] = a; }
      }
      __syncthreads();
    }
  }
  {
#pragma clang fp contract(off)
    for (int s = tid; s < SELN; s += 1024) {
      u64 key = sortbuf[SW(s)];
      int e = (int)(~(u32)(key & 0xFFFFFFFFull));
      top_idx[b * PRE + s] = e;
      top_score[b * PRE + s] = sc[e];
      const float* bx = boxes + ((size_t)b * NN + e) * 7;
      float x = bx[0], y = bx[1], dx = bx[3], dy = bx[4];
      float hx = dx * 0.5f, hy = dy * 0.5f;
      bx1[b * PRE + s] = x - hx;
      bx2[b * PRE + s] = x + hx;
      by1[b * PRE + s] = y - hy;
      by2[b * PRE + s] = y + hy;
      bar[b * PRE + s] = dx * dy;
    }
  }
}

// ---------------- suppression bitmask (iou > 0.7, j > i) --------------------
__device__ __forceinline__ void mask_tile(
    const float* __restrict__ bx1, const float* __restrict__ bx2,
    const float* __restrict__ by1, const float* __restrict__ by2,
    const float* __restrict__ bar, u64* __restrict__ mask,
    int b, int rb, int cb, int t) {
#pragma clang fp contract(off)
  int i = rb * 64 + t;
  int j0 = cb * 64 + t;
  float cx1 = bx1[b * PRE + j0], cx2 = bx2[b * PRE + j0];
  float cy1 = by1[b * PRE + j0], cy2 = by2[b * PRE + j0];
  float car = bar[b * PRE + j0];
  float ix1 = bx1[b * PRE + i], ix2 = bx2[b * PRE + i];
  float iy1 = by1[b * PRE + i], iy2 = by2[b * PRE + i];
  float ia = bar[b * PRE + i];
  u64 bits = 0ull;
  int jbase = cb * 64;
  for (int jj = 0; jj < 64; ++jj) {
    float jx1 = __shfl(cx1, jj, 64);
    float jx2 = __shfl(cx2, jj, 64);
    float jy1 = __shfl(cy1, jj, 64);
    float jy2 = __shfl(cy2, jj, 64);
    float jar = __shfl(car, jj, 64);
    if (jbase + jj > i) {
      float iw = fminf(ix2, jx2) - fmaxf(ix1, jx1);
      iw = fmaxf(iw, 0.0f);
      float ih = fminf(iy2, jy2) - fmaxf(iy1, jy1);
      ih = fmaxf(ih, 0.0f);
      float inter = iw * ih;
      float uni = ia + jar - inter;
      float iou = inter / fmaxf(uni, 1e-6f);
      if (iou > 0.7f) bits |= (1ull << jj);
    }
  }
  mask[((size_t)b * PRE + i) * NW + cb] = bits;
}

__global__ void mask_prefix_kernel(const float* __restrict__ bx1, const float* __restrict__ bx2,
                                   const float* __restrict__ by1, const float* __restrict__ by2,
                                   const float* __restrict__ bar, u64* __restrict__ mask) {
  int cb = blockIdx.x, rb = blockIdx.y, b = blockIdx.z;
  if (cb < rb) return;
  mask_tile(bx1, bx2, by1, by2, bar, mask, b, rb, cb, threadIdx.x);
}

// gated fallback: grid-strided (small dispatch when gated; never runs here)
__global__ __launch_bounds__(256) void mask_full_kernel(
    const float* __restrict__ bx1, const float* __restrict__ bx2,
    const float* __restrict__ by1, const float* __restrict__ by2,
    const float* __restrict__ bar, u64* __restrict__ mask,
    const int* __restrict__ st_info) {
  int b = blockIdx.y;
  if (st_info[b * 2 + 0] >= POST) return;
  int cb = blockIdx.x * 4 + (threadIdx.x >> 6);
  int t = threadIdx.x & 63;
  for (int rb = 0; rb <= cb; ++rb)
    mask_tile(bx1, bx2, by1, by2, bar, mask, b, rb, cb, t);
}

// ---------------- chunked greedy NMS, 4 waves per batch ---------------------
template<bool FULL>
__global__ __launch_bounds__(256) void nms_kernel_t(
    const u64* __restrict__ mask, u64* __restrict__ keep_words,
    int* __restrict__ st_info) {
  int b = blockIdx.x;
  if (FULL && st_info[b * 2 + 0] >= POST) return;  // hot path already done
  int tid = threadIdx.x;
  int lane = tid & 63;
  int wv = tid >> 6;
  __shared__ u64 part[2][4][64];

  const u64* base = mask + (size_t)b * PRE * NW;
  u64 rem = 0ull, keepw = 0ull;
  int kept = 0;
  const int c1 = FULL ? NW : PREF_CH;

  int c = 0;
  while (c < c1) {
    u64 remc = __shfl(rem, c, 64);
    const u64* rowp = base + ((size_t)(c * 64 + wv * 16)) * NW + lane;
    u64 m[16];
#pragma unroll
    for (int k = 0; k < 16; ++k) m[k] = rowp[(size_t)k * NW];
    u64 dg = base[((size_t)(c * 64 + lane)) * NW + c];
    u64 nz = __ballot(dg != 0ull);
    while (nz) {
      int i2 = __builtin_ctzll(nz);
      nz &= nz - 1ull;
      u64 di = __shfl(dg, i2, 64);
      if (!((remc >> i2) & 1ull)) remc |= di;
    }
    u64 K = ~remc;
    if (lane == c) keepw = K;
    kept += __popcll(K);

    u32 kb = (u32)((K >> (wv * 16)) & 0xFFFFull);
    u64 acc = 0ull;
#pragma unroll
    for (int k = 0; k < 16; ++k)
      if ((kb >> k) & 1u) acc |= m[k];
    part[c & 1][wv][lane] = acc;
    __syncthreads();
    rem |= part[c & 1][0][lane] | part[c & 1][1][lane] |
           part[c & 1][2][lane] | part[c & 1][3][lane];
    ++c;
    if (kept >= POST) break;  // uniform; later output ranks all >= POST
  }

  if (wv == 0) {
    keep_words[b * 64 + lane] = keepw;  // unprocessed chunks -> 0
    if (!FULL && lane == 0) st_info[b * 2 + 0] = kept;
  }
}

// ---------------- emit first POST kept entries ------------------------------
__global__ __launch_bounds__(1024) void output_kernel(
    const u64* __restrict__ keep_words, const int* __restrict__ top_idx,
    const float* __restrict__ top_score, const int* __restrict__ labels,
    const float* __restrict__ boxes, float* __restrict__ out) {
  int b = blockIdx.x, tid = threadIdx.x;
  __shared__ u32 scanbuf[1024];
  __shared__ int sh_total;

  u64 w = keep_words[b * 64 + (tid >> 4)];
  u32 my4 = (u32)((w >> ((tid & 15) * 4)) & 0xFull);  // 4 consecutive i per thread
  int cnt = __popc(my4);
  scanbuf[tid] = (u32)cnt;
  __syncthreads();
  for (int off = 1; off < 1024; off <<= 1) {
    u32 v = scanbuf[tid];
    u32 add = (tid >= off) ? scanbuf[tid - off] : 0u;
    __syncthreads();
    scanbuf[tid] = v + add;
    __syncthreads();
  }
  int base = (int)scanbuf[tid] - cnt;
  if (tid == 1023) sh_total = (int)scanbuf[1023];
  __syncthreads();
  int total = sh_total;

  float* rois = out;                 // BB*POST*7
  float* rsc = out + BB * POST * 7;  // BB*POST
  float* rlb = rsc + BB * POST;      // BB*POST (labels as f32)

  int r = 0;
  for (int k = 0; k < 4; ++k) {
    if ((my4 >> k) & 1u) {
      int rank = base + (r++);
      if (rank < POST) {
        int i = tid * 4 + k;
        int idx = top_idx[b * PRE + i];
        const float* bx = boxes + ((size_t)b * NN + idx) * 7;
        float* ro = rois + ((size_t)b * POST + rank) * 7;
        for (int c = 0; c < 7; ++c) ro[c] = bx[c];
        rsc[b * POST + rank] = top_score[b * PRE + i];
        rlb[b * POST + rank] = (float)(labels[b * NN + idx] + 1);
      }
    }
  }
  // invalid slots: rois = 0, score = 0, label = 0 + 1
  for (int s = tid; s < POST; s += 1024) {
    if (s >= total) {
      float* ro = rois + ((size_t)b * POST + s) * 7;
      for (int c = 0; c < 7; ++c) ro[c] = 0.0f;
      rsc[b * POST + s] = 0.0f;
      rlb[b * POST + s] = 1.0f;
    }
  }
}

// ---------------------------------------------------------------------------
extern "C" void kernel_launch(void* const* d_in, const int* in_sizes, int n_in,
                              void* d_out, int out_size, void* d_ws, size_t ws_size,
                              hipStream_t stream) {
  const float* boxes = (const float*)d_in[0];  // (B, N, 7)
  const float* cls = (const float*)d_in[1];    // (B, N, 3)
  float* out = (float*)d_out;                  // rois | scores | labels, flat f32

  char* w = (char*)d_ws;
  float* scores = (float*)w;    w += (size_t)BB * NN * 4;
  int* labels = (int*)w;        w += (size_t)BB * NN * 4;
  int* top_idx = (int*)w;       w += (size_t)BB * PRE * 4;
  float* top_score = (float*)w; w += (size_t)BB * PRE * 4;
  float* bx1 = (float*)w;       w += (size_t)BB * PRE * 4;
  float* bx2 = (float*)w;       w += (size_t)BB * PRE * 4;
  float* by1 = (float*)w;       w += (size_t)BB * PRE * 4;
  float* by2 = (float*)w;       w += (size_t)BB * PRE * 4;
  float* bar = (float*)w;       w += (size_t)BB * PRE * 4;
  u64* mask = (u64*)w;          w += (size_t)BB * PRE * NW * 8;
  u64* keepw = (u64*)w;         w += (size_t)BB * 64 * 8;
  int* st_info = (int*)w;       w += (size_t)BB * 2 * 4;
  u32* bhist = (u32*)w;         w += (size_t)BB * 16 * NBIN * 4;
  u64* cand = (u64*)w;          w += (size_t)BB * PSEL * 8;
  u64* ceq = (u64*)w;           w += (size_t)BB * CEQ * 8;
  int* st2 = (int*)w;           w += (size_t)BB * 2 * 4;
  u32* gcnt = (u32*)w;          w += (size_t)BB * 2 * 4;

  // hot path: multi-block top-1024 selection pipeline
  prep_kernel<<<dim3(16, BB), 256, 0, stream>>>(cls, scores, labels, bhist);
  pivot_kernel<<<BB, 256, 0, stream>>>(bhist, st2, gcnt);
  compact_kernel<<<dim3(16, BB), 256, 0, stream>>>(scores, st2, gcnt, cand, ceq);
  sort1024_kernel<<<BB, 1024, 0, stream>>>(boxes, st2, gcnt, cand, ceq,
                                           top_idx, top_score, bx1, bx2, by1, by2, bar);
  mask_prefix_kernel<<<dim3(PREF_CH, PREF_CH, BB), 64, 0, stream>>>(
      bx1, bx2, by1, by2, bar, mask);
  nms_kernel_t<false><<<BB, 256, 0, stream>>>(mask, keepw, st_info);
  // fallback chain (exits immediately when prefix found >= POST keepers)
  select_kernel_t<PRE, true><<<BB, 1024, 0, stream>>>(
      scores, boxes, st_info, top_idx, top_score, bx1, bx2, by1, by2, bar);
  mask_full_kernel<<<dim3(16, BB), 256, 0, stream>>>(
      bx1, bx2, by1, by2, bar, mask, st_info);
  nms_kernel_t<true><<<BB, 256, 0, stream>>>(mask, keepw, st_info);
  // output
  output_kernel<<<BB, 1024, 0, stream>>>(keepw, top_idx, top_score, labels, boxes, out);
}

// Round 12
// 115.297 us; speedup vs baseline: 1.2894x; 1.0772x over previous
//
#include <hip/hip_runtime.h>
#include <cstdint>
#include <cstddef>

#define BB 4
#define NN 32768
#define PRE 4096
#define POST 512
#define NW 64        // u64 words per full mask row = PRE/64
#define PSEL 1024    // prefix selection size (hot path)
#define PREF_CH 16   // PSEL/64 chunks
#define NBIN 4096    // 12-bit bins (enc >> 20)
#define CEQ 32768    // eq-bin candidate capacity (cannot overflow)

typedef unsigned long long u64;
typedef unsigned int u32;
typedef float f4u __attribute__((ext_vector_type(4), aligned(4)));  // 4B-aligned float4

// LDS bank-conflict swizzle for the fallback's u64 sort buffer
#define SW(i) ((i) ^ (((i) >> 4) & 15))

__device__ __forceinline__ u32 enc_f32(float f) {
  u32 u = __float_as_uint(f);
  u32 m = (u32)((int)u >> 31) | 0x80000000u;  // neg -> 0xFFFFFFFF, pos -> 0x80000000
  return u ^ m;                                // ascending u <=> ascending f
}
// exact inverse of enc_f32 (bijection, bit-exact; verified R10)
__device__ __forceinline__ float dec_f32(u32 e) {
  u32 u = (e & 0x80000000u) ? (e ^ 0x80000000u) : ~e;
  return __uint_as_float(u);
}

// ======== kernel 1: scores/labels from cls + per-block 4096-bin hist ========
__global__ __launch_bounds__(256) void prep_kernel(
    const float* __restrict__ cls, float* __restrict__ scores,
    int* __restrict__ labels, u32* __restrict__ bhist) {
  int blk = blockIdx.x, b = blockIdx.y;
  int tid = threadIdx.x;
  __shared__ u32 lhist[NBIN];
  for (int i = tid; i < NBIN; i += 256) lhist[i] = 0;
  __syncthreads();

  const int E = blk * 2048 + tid * 8;  // batch-relative element
  const float4* cp4 = (const float4*)(cls + ((size_t)b * NN + E) * 3);
  float4 v0 = cp4[0], v1 = cp4[1], v2 = cp4[2], v3 = cp4[3], v4 = cp4[4], v5 = cp4[5];
  float fa[24] = {v0.x, v0.y, v0.z, v0.w, v1.x, v1.y, v1.z, v1.w,
                  v2.x, v2.y, v2.z, v2.w, v3.x, v3.y, v3.z, v3.w,
                  v4.x, v4.y, v4.z, v4.w, v5.x, v5.y, v5.z, v5.w};
  float sc8[8];
  int lb8[8];
#pragma unroll
  for (int k = 0; k < 8; ++k) {
    float c0 = fa[3 * k], c1 = fa[3 * k + 1], c2 = fa[3 * k + 2];
    float m = c0; int l = 0;
    if (c1 > m) { m = c1; l = 1; }
    if (c2 > m) { m = c2; l = 2; }
    sc8[k] = m;
    lb8[k] = l;
    atomicAdd(&lhist[enc_f32(m) >> 20], 1u);
  }
  float4* so = (float4*)(scores + (size_t)b * NN + E);
  so[0] = make_float4(sc8[0], sc8[1], sc8[2], sc8[3]);
  so[1] = make_float4(sc8[4], sc8[5], sc8[6], sc8[7]);
  int4* lo = (int4*)(labels + (size_t)b * NN + E);
  lo[0] = make_int4(lb8[0], lb8[1], lb8[2], lb8[3]);
  lo[1] = make_int4(lb8[4], lb8[5], lb8[6], lb8[7]);
  __syncthreads();
  u32* row = bhist + (size_t)(b * 16 + blk) * NBIN;
  for (int i = tid; i < NBIN; i += 256) row[i] = lhist[i];
}

// ======== hybrid bitonic sort of 1024 u64, 1 elem/thread (proven r6..r10) ===
__device__ __forceinline__ u64 hybrid_sort1024(u64 key, u64* sortbuf, int tid) {
#pragma unroll
  for (int k2 = 2; k2 <= 64; k2 <<= 1) {
    for (int j = k2 >> 1; j > 0; j >>= 1) {
      u64 o = __shfl_xor(key, j, 64);
      bool take_max = (((tid & k2) == 0) == ((tid & j) == 0));
      key = ((key > o) == take_max) ? key : o;
    }
  }
  for (int k2 = 128; k2 <= PSEL; k2 <<= 1) {
    for (int j = k2 >> 1; j >= 64; j >>= 1) {
      __syncthreads();
      sortbuf[tid] = key;
      __syncthreads();
      u64 o = sortbuf[tid ^ j];
      bool take_max = (((tid & k2) == 0) == ((tid & j) == 0));
      key = ((key > o) == take_max) ? key : o;
    }
    for (int j = 32; j > 0; j >>= 1) {
      u64 o = __shfl_xor(key, j, 64);
      bool take_max = (((tid & k2) == 0) == ((tid & j) == 0));
      key = ((key > o) == take_max) ? key : o;
    }
  }
  return key;
}

// ======== kernel 2: fused pivot + compact + sort (grid BB x 1024) ===========
// Placement order in ebuf/ceq is irrelevant: keys are unique and both
// partitions are fully sorted downstream, so unordered atomic counters are
// exact (same selected set, same final order).
__global__ __launch_bounds__(1024) void selsort_kernel(
    const float* __restrict__ scores, const float* __restrict__ boxes,
    const u32* __restrict__ bhist, u64* __restrict__ ceq,
    int* __restrict__ top_idx, float* __restrict__ top_score,
    float* __restrict__ bx1, float* __restrict__ bx2,
    float* __restrict__ by1, float* __restrict__ by2, float* __restrict__ bar) {
  int b = blockIdx.x;
  int tid = threadIdx.x, lane = tid & 63;
  __shared__ u64 sortbuf[PSEL];   // sort scratch
  __shared__ u64 ebuf[PSEL];      // assembled final candidate keys
  __shared__ u32 ssum[1024];      // suffix-scan buffer
  __shared__ int sh_pb, sh_need;
  __shared__ u32 sh_cg, sh_cm;

  // --- pivot: sum the 16 block-hists; suffix-scan 4096 bins (4 bins/thread) ---
  u32 s0 = 0, s1 = 0, s2 = 0, s3 = 0;
#pragma unroll
  for (int k = 0; k < 16; ++k) {
    const u32* hb = bhist + (size_t)(b * 16 + k) * NBIN + tid * 4;
    s0 += hb[0]; s1 += hb[1]; s2 += hb[2]; s3 += hb[3];
  }
  ssum[tid] = s0 + s1 + s2 + s3;
  __syncthreads();
  for (int off = 1; off < 1024; off <<= 1) {
    u32 v = ssum[tid];
    u32 a = (tid + off < 1024) ? ssum[tid + off] : 0u;
    __syncthreads();
    ssum[tid] = v + a;
    __syncthreads();
  }
  {
    u32 cum = (tid < 1023) ? ssum[tid + 1] : 0u;  // all bins beyond my 4
    u32 incl;
    incl = cum + s3; if (incl >= (u32)PSEL && cum < (u32)PSEL) { sh_pb = tid * 4 + 3; sh_need = PSEL - (int)cum; } cum = incl;
    incl = cum + s2; if (incl >= (u32)PSEL && cum < (u32)PSEL) { sh_pb = tid * 4 + 2; sh_need = PSEL - (int)cum; } cum = incl;
    incl = cum + s1; if (incl >= (u32)PSEL && cum < (u32)PSEL) { sh_pb = tid * 4 + 1; sh_need = PSEL - (int)cum; } cum = incl;
    incl = cum + s0; if (incl >= (u32)PSEL && cum < (u32)PSEL) { sh_pb = tid * 4 + 0; sh_need = PSEL - (int)cum; } cum = incl;
  }
  if (tid == 0) { sh_cg = 0; sh_cm = 0; }
  __syncthreads();
  const u32 pb = (u32)sh_pb;

  // --- compact: 32 scores/thread; wave shfl-scan + 2 LDS atomics per wave ---
  u32 encs[32];
  {
    const float4* sc4 = (const float4*)(scores + (size_t)b * NN + tid * 32);
#pragma unroll
    for (int k = 0; k < 8; ++k) {
      float4 v = sc4[k];
      encs[k * 4 + 0] = enc_f32(v.x);
      encs[k * 4 + 1] = enc_f32(v.y);
      encs[k * 4 + 2] = enc_f32(v.z);
      encs[k * 4 + 3] = enc_f32(v.w);
    }
  }
  u32 gtl = 0, eql = 0;
#pragma unroll
  for (int k = 0; k < 32; ++k) {
    u32 bin = encs[k] >> 20;
    gtl += (bin > pb);
    eql += (bin == pb);
  }
  u64 pack = ((u64)gtl << 32) | eql;
#pragma unroll
  for (int off = 1; off < 64; off <<= 1) {
    u64 t = __shfl_up(pack, off, 64);
    if (lane >= off) pack += t;
  }
  u64 tot = __shfl(pack, 63, 64);
  u32 bg = 0, be = 0;
  if (lane == 63) {
    bg = atomicAdd(&sh_cg, (u32)(tot >> 32));
    be = atomicAdd(&sh_cm, (u32)(tot & 0xFFFFFFFFu));
  }
  bg = (u32)__shfl((int)bg, 63, 64);
  be = (u32)__shfl((int)be, 63, 64);
  int pg = (int)(bg + (u32)(pack >> 32) - gtl);
  int pe = (int)(be + (u32)(pack & 0xFFFFFFFFu) - eql);
#pragma unroll
  for (int k = 0; k < 32; ++k) {
    u32 bin = encs[k] >> 20;
    u64 key = ((u64)encs[k] << 32) | (u32)(~(u32)(tid * 32 + k));
    if (bin > pb) ebuf[pg++] = key;
    else if (bin == pb) ceq[(size_t)b * CEQ + (pe++)] = key;
  }
  __syncthreads();

  const int g = (int)sh_cg;     // count in bins > pb ( < PSEL by crossing )
  const int m = (int)sh_cm;     // count in pivot bin ( >= need )
  const int need = sh_need;     // g + need == PSEL

  if (m <= PSEL) {  // common case: sort the pivot bin, take its top-need
    u64 ek = (tid < m) ? ceq[(size_t)b * CEQ + tid] : 0ull;
    ek = hybrid_sort1024(ek, sortbuf, tid);   // ek = tid-th largest eq key
    if (tid < need) ebuf[g + tid] = ek;
  } else {          // rare: rank by scan (exact for any m)
    const int qmax = (m + 1023) >> 10;
    for (int q = 0; q < qmax; ++q) {
      int i = q * 1024 + tid;
      u64 kk = (i < m) ? ceq[(size_t)b * CEQ + i] : 0ull;
      u32 rr = 0;
      for (int base2 = 0; base2 < m; base2 += 1024) {
        int cn = min(1024, m - base2);
        __syncthreads();
        if (tid < cn) sortbuf[tid] = ceq[(size_t)b * CEQ + base2 + tid];
        __syncthreads();
        for (int j = 0; j < cn; ++j) rr += (sortbuf[j] > kk);
      }
      if (i < m && rr < (u32)need) ebuf[g + rr] = kk;  // ranks unique
    }
  }
  __syncthreads();

  u64 key = ebuf[tid];
  key = hybrid_sort1024(key, sortbuf, tid);

  // --- epilogue: score decoded from key; box via two 4B-aligned float4 ---
  {
#pragma clang fp contract(off)
    u32 ue = (u32)(key >> 32);
    int e = (int)(~(u32)key);
    top_idx[b * PRE + tid] = e;
    top_score[b * PRE + tid] = dec_f32(ue);
    const float* bx = boxes + ((size_t)b * NN + e) * 7;
    f4u p0 = *(const f4u*)(bx);       // x, y, z, dx
    f4u p1 = *(const f4u*)(bx + 3);   // dx, dy, dz, heading
    float x = p0.x, y = p0.y, dx = p0.w, dy = p1.y;
    float hx = dx * 0.5f, hy = dy * 0.5f;
    bx1[b * PRE + tid] = x - hx;
    bx2[b * PRE + tid] = x + hx;
    by1[b * PRE + tid] = y - hy;
    by2[b * PRE + tid] = y + hy;
    bar[b * PRE + tid] = dx * dy;
  }
}

// ======== cold fallback: round-4 top-PRE select (gated) =====================
template<int SELN, bool GATED>
__global__ __launch_bounds__(1024) void select_kernel_t(
    const float* __restrict__ scores, const float* __restrict__ boxes,
    const int* __restrict__ st_info,
    int* __restrict__ top_idx, float* __restrict__ top_score,
    float* __restrict__ bx1, float* __restrict__ bx2,
    float* __restrict__ by1, float* __restrict__ by2, float* __restrict__ bar) {
  int b = blockIdx.x;
  if (GATED && st_info[b * 2 + 0] >= POST) return;  // fallback not needed
  int tid = threadIdx.x;
  int wv = tid >> 6;
  const float* sc = scores + (size_t)b * NN;

  __shared__ u32 hist16[16][256];   // per-wave privatized histograms
  __shared__ u32 sA[256], sB[256];  // suffix-scan ping-pong
  __shared__ u32 scanbuf[1024];
  __shared__ u64 sortbuf[SELN];
  __shared__ u32 sh_prefix;
  __shared__ int sh_rem;

  const int e0 = tid * 32;
  u32 encs[32];
  {
    const float4* sc4 = (const float4*)(sc + e0);
#pragma unroll
    for (int k = 0; k < 8; ++k) {
      float4 v = sc4[k];
      encs[k * 4 + 0] = enc_f32(v.x);
      encs[k * 4 + 1] = enc_f32(v.y);
      encs[k * 4 + 2] = enc_f32(v.z);
      encs[k * 4 + 3] = enc_f32(v.w);
    }
  }

  u32 prefix = 0, known = 0;
  int remaining = SELN;
  for (int shift = 24; shift >= 0; shift -= 8) {
    for (int k = tid; k < 16 * 256; k += 1024) ((u32*)hist16)[k] = 0;
    __syncthreads();
#pragma unroll
    for (int k = 0; k < 32; ++k) {
      u32 u = encs[k];
      if ((u & known) == prefix) atomicAdd(&hist16[wv][(u >> shift) & 255u], 1u);
    }
    __syncthreads();
    if (tid < 256) {
      u32 t = 0;
#pragma unroll
      for (int w2 = 0; w2 < 16; ++w2) t += hist16[w2][tid];
      sA[tid] = t;
    }
    __syncthreads();
    u32* src = sA; u32* dst = sB;
    for (int off = 1; off < 256; off <<= 1) {
      if (tid < 256) dst[tid] = src[tid] + ((tid + off < 256) ? src[tid + off] : 0u);
      __syncthreads();
      u32* tp = src; src = dst; dst = tp;
    }
    if (tid < 256) {
      u32 sv = src[tid];
      u32 svn = (tid < 255) ? src[tid + 1] : 0u;
      if (sv >= (u32)remaining && svn < (u32)remaining) {
        sh_prefix = prefix | ((u32)tid << shift);
        sh_rem = remaining - (int)svn;
      }
    }
    __syncthreads();
    prefix = sh_prefix;
    remaining = sh_rem;
    known |= (0xFFu << shift);
    __syncthreads();
  }
  const u32 pivot = prefix;

  int gtc = 0, eqc = 0;
#pragma unroll
  for (int k = 0; k < 32; ++k) {
    gtc += (encs[k] > pivot);
    eqc += (encs[k] == pivot);
  }
  scanbuf[tid] = ((u32)gtc << 16) | (u32)eqc;
  __syncthreads();
  for (int off = 1; off < 1024; off <<= 1) {
    u32 v = scanbuf[tid];
    u32 add = (tid >= off) ? scanbuf[tid - off] : 0u;
    __syncthreads();
    scanbuf[tid] = v + add;
    __syncthreads();
  }
  u32 incl = scanbuf[tid];
  u32 totpk = scanbuf[1023];
  const int cnt_gt = (int)(totpk >> 16);
  int gt_base = (int)(incl >> 16) - gtc;
  int eq_base = (int)(incl & 0xFFFFu) - eqc;
  int gs = 0, es = 0;
#pragma unroll
  for (int k = 0; k < 32; ++k) {
    u32 u = encs[k];
    int e = e0 + k;
    u64 key = ((u64)u << 32) | (u32)(~(u32)e);
    if (u > pivot) {
      sortbuf[SW(gt_base + gs)] = key; gs++;
    } else if (u == pivot) {
      int g = eq_base + (es++);
      if (g < remaining) sortbuf[SW(cnt_gt + g)] = key;
    }
  }
  __syncthreads();

  for (int k = 2; k <= SELN; k <<= 1) {
    for (int j = k >> 1; j > 0; j >>= 1) {
      for (int p = tid; p < SELN / 2; p += 1024) {
        int low = p & (j - 1);
        int i = ((p ^ low) << 1) | low;
        int ixj = i + j;
        u64 a = sortbuf[SW(i)], c = sortbuf[SW(ixj)];
        bool desc = ((i & k) == 0);
        if (desc ? (a < c) : (a > c)) { sortbuf[SW(i)] = c; sortbuf[SW(ixj)] = a; }
      }
      __syncthreads();
    }
  }
  {
#pragma clang fp contract(off)
    for (int s = tid; s < SELN; s += 1024) {
      u64 key = sortbuf[SW(s)];
      int e = (int)(~(u32)(key & 0xFFFFFFFFull));
      top_idx[b * PRE + s] = e;
      top_score[b * PRE + s] = sc[e];
      const float* bx = boxes + ((size_t)b * NN + e) * 7;
      float x = bx[0], y = bx[1], dx = bx[3], dy = bx[4];
      float hx = dx * 0.5f, hy = dy * 0.5f;
      bx1[b * PRE + s] = x - hx;
      bx2[b * PRE + s] = x + hx;
      by1[b * PRE + s] = y - hy;
      by2[b * PRE + s] = y + hy;
      bar[b * PRE + s] = dx * dy;
    }
  }
}

// ---------------- suppression bitmask (iou > 0.7, j > i) --------------------
__device__ __forceinline__ void mask_tile(
    const float* __restrict__ bx1, const float* __restrict__ bx2,
    const float* __restrict__ by1, const float* __restrict__ by2,
    const float* __restrict__ bar, u64* __restrict__ mask,
    int b, int rb, int cb, int t) {
#pragma clang fp contract(off)
  int i = rb * 64 + t;
  int j0 = cb * 64 + t;
  float cx1 = bx1[b * PRE + j0], cx2 = bx2[b * PRE + j0];
  float cy1 = by1[b * PRE + j0], cy2 = by2[b * PRE + j0];
  float car = bar[b * PRE + j0];
  float ix1 = bx1[b * PRE + i], ix2 = bx2[b * PRE + i];
  float iy1 = by1[b * PRE + i], iy2 = by2[b * PRE + i];
  float ia = bar[b * PRE + i];
  u64 bits = 0ull;
  int jbase = cb * 64;
  for (int jj = 0; jj < 64; ++jj) {
    float jx1 = __shfl(cx1, jj, 64);
    float jx2 = __shfl(cx2, jj, 64);
    float jy1 = __shfl(cy1, jj, 64);
    float jy2 = __shfl(cy2, jj, 64);
    float jar = __shfl(car, jj, 64);
    if (jbase + jj > i) {
      float iw = fminf(ix2, jx2) - fmaxf(ix1, jx1);
      iw = fmaxf(iw, 0.0f);
      float ih = fminf(iy2, jy2) - fmaxf(iy1, jy1);
      ih = fmaxf(ih, 0.0f);
      float inter = iw * ih;
      float uni = ia + jar - inter;
      float iou = inter / fmaxf(uni, 1e-6f);
      if (iou > 0.7f) bits |= (1ull << jj);
    }
  }
  mask[((size_t)b * PRE + i) * NW + cb] = bits;
}

__global__ void mask_prefix_kernel(const float* __restrict__ bx1, const float* __restrict__ bx2,
                                   const float* __restrict__ by1, const float* __restrict__ by2,
                                   const float* __restrict__ bar, u64* __restrict__ mask) {
  int cb = blockIdx.x, rb = blockIdx.y, b = blockIdx.z;
  if (cb < rb) return;
  mask_tile(bx1, bx2, by1, by2, bar, mask, b, rb, cb, threadIdx.x);
}

// gated fallback: grid-strided (small dispatch when gated; never runs here)
__global__ __launch_bounds__(256) void mask_full_kernel(
    const float* __restrict__ bx1, const float* __restrict__ bx2,
    const float* __restrict__ by1, const float* __restrict__ by2,
    const float* __restrict__ bar, u64* __restrict__ mask,
    const int* __restrict__ st_info) {
  int b = blockIdx.y;
  if (st_info[b * 2 + 0] >= POST) return;
  int cb = blockIdx.x * 4 + (threadIdx.x >> 6);
  int t = threadIdx.x & 63;
  for (int rb = 0; rb <= cb; ++rb)
    mask_tile(bx1, bx2, by1, by2, bar, mask, b, rb, cb, t);
}

// ---------------- chunked greedy NMS, 4 waves per batch ---------------------
// Prefix variant: only mask words 0..15 exist (PSEL=1024); wave = 4 row-groups
// x 16 words (lane = g*16 + w), 4 loads/lane = 16 rows/wave, shfl_xor combine.
template<bool FULL>
__global__ __launch_bounds__(256) void nms_kernel_t(
    const u64* __restrict__ mask, u64* __restrict__ keep_words,
    int* __restrict__ st_info) {
  int b = blockIdx.x;
  if (FULL && st_info[b * 2 + 0] >= POST) return;  // hot path already done
  int tid = threadIdx.x;
  int lane = tid & 63;
  int wv = tid >> 6;

  const u64* base = mask + (size_t)b * PRE * NW;
  u64 rem = 0ull, keepw = 0ull;
  int kept = 0;
  int c = 0;

  if constexpr (!FULL) {
    __shared__ u64 part[2][4][16];
    const int g16 = lane >> 4;   // row subgroup 0..3
    const int w = lane & 15;     // word 0..15
    while (c < PREF_CH) {
      u64 remc = __shfl(rem, c, 64);  // rem replicated every 16 lanes
      // 4 loads/lane: rows wv*16 + k*4 + g16, word w
      const u64* rowb = base + ((size_t)(c * 64 + wv * 16)) * NW + w;
      u64 m0 = rowb[(size_t)(0 + g16) * NW];
      u64 m1 = rowb[(size_t)(4 + g16) * NW];
      u64 m2 = rowb[(size_t)(8 + g16) * NW];
      u64 m3 = rowb[(size_t)(12 + g16) * NW];
      // diagonal word of row (c*64+lane): within-chunk suppression candidates
      u64 dg = base[((size_t)(c * 64 + lane)) * NW + c];
      u64 nz = __ballot(dg != 0ull);
      while (nz) {
        int i2 = __builtin_ctzll(nz);
        nz &= nz - 1ull;
        u64 di = __shfl(dg, i2, 64);
        if (!((remc >> i2) & 1ull)) remc |= di;
      }
      u64 K = ~remc;
      if (lane == c) keepw = K;
      kept += __popcll(K);

      u64 acc = 0ull;
      if ((K >> (wv * 16 + 0 + g16)) & 1ull) acc |= m0;
      if ((K >> (wv * 16 + 4 + g16)) & 1ull) acc |= m1;
      if ((K >> (wv * 16 + 8 + g16)) & 1ull) acc |= m2;
      if ((K >> (wv * 16 + 12 + g16)) & 1ull) acc |= m3;
      acc |= __shfl_xor(acc, 16, 64);
      acc |= __shfl_xor(acc, 32, 64);   // all lanes: OR over wave's 16 rows for word (lane&15)
      if (g16 == 0) part[c & 1][wv][w] = acc;
      __syncthreads();
      rem |= part[c & 1][0][w] | part[c & 1][1][w] |
             part[c & 1][2][w] | part[c & 1][3][w];
      ++c;
      if (kept >= POST) break;  // uniform
    }
  } else {
    __shared__ u64 part[2][4][64];
    while (c < NW) {
      u64 remc = __shfl(rem, c, 64);
      const u64* rowp = base + ((size_t)(c * 64 + wv * 16)) * NW + lane;
      u64 m[16];
#pragma unroll
      for (int k = 0; k < 16; ++k) m[k] = rowp[(size_t)k * NW];
      u64 dg = base[((size_t)(c * 64 + lane)) * NW + c];
      u64 nz = __ballot(dg != 0ull);
      while (nz) {
        int i2 = __builtin_ctzll(nz);
        nz &= nz - 1ull;
        u64 di = __shfl(dg, i2, 64);
        if (!((remc >> i2) & 1ull)) remc |= di;
      }
      u64 K = ~remc;
      if (lane == c) keepw = K;
      kept += __popcll(K);

      u32 kb = (u32)((K >> (wv * 16)) & 0xFFFFull);
      u64 acc = 0ull;
#pragma unroll
      for (int k = 0; k < 16; ++k)
        if ((kb >> k) & 1u) acc |= m[k];
      part[c & 1][wv][lane] = acc;
      __syncthreads();
      rem |= part[c & 1][0][lane] | part[c & 1][1][lane] |
             part[c & 1][2][lane] | part[c & 1][3][lane];
      ++c;
      if (kept >= POST) break;  // uniform
    }
  }

  if (wv == 0) {
    keep_words[b * 64 + lane] = keepw;  // unprocessed chunks -> 0
    if (!FULL && lane == 0) st_info[b * 2 + 0] = kept;
  }
}

// ---------------- emit first POST kept entries ------------------------------
__global__ __launch_bounds__(1024) void output_kernel(
    const u64* __restrict__ keep_words, const int* __restrict__ top_idx,
    const float* __restrict__ top_score, const int* __restrict__ labels,
    const float* __restrict__ boxes, float* __restrict__ out) {
  int b = blockIdx.x, tid = threadIdx.x;
  __shared__ u32 scanbuf[1024];
  __shared__ int sh_total;

  u64 w = keep_words[b * 64 + (tid >> 4)];
  u32 my4 = (u32)((w >> ((tid & 15) * 4)) & 0xFull);  // 4 consecutive i per thread
  int cnt = __popc(my4);
  scanbuf[tid] = (u32)cnt;
  __syncthreads();
  for (int off = 1; off < 1024; off <<= 1) {
    u32 v = scanbuf[tid];
    u32 add = (tid >= off) ? scanbuf[tid - off] : 0u;
    __syncthreads();
    scanbuf[tid] = v + add;
    __syncthreads();
  }
  int base = (int)scanbuf[tid] - cnt;
  if (tid == 1023) sh_total = (int)scanbuf[1023];
  __syncthreads();
  int total = sh_total;

  float* rois = out;                 // BB*POST*7
  float* rsc = out + BB * POST * 7;  // BB*POST
  float* rlb = rsc + BB * POST;      // BB*POST (labels as f32)

  int r = 0;
  for (int k = 0; k < 4; ++k) {
    if ((my4 >> k) & 1u) {
      int rank = base + (r++);
      if (rank < POST) {
        int i = tid * 4 + k;
        int idx = top_idx[b * PRE + i];
        const float* bx = boxes + ((size_t)b * NN + idx) * 7;
        float* ro = rois + ((size_t)b * POST + rank) * 7;
        for (int c = 0; c < 7; ++c) ro[c] = bx[c];
        rsc[b * POST + rank] = top_score[b * PRE + i];
        rlb[b * POST + rank] = (float)(labels[b * NN + idx] + 1);
      }
    }
  }
  // invalid slots: rois = 0, score = 0, label = 0 + 1
  for (int s = tid; s < POST; s += 1024) {
    if (s >= total) {
      float* ro = rois + ((size_t)b * POST + s) * 7;
      for (int c = 0; c < 7; ++c) ro[c] = 0.0f;
      rsc[b * POST + s] = 0.0f;
      rlb[b * POST + s] = 1.0f;
    }
  }
}

// ---------------------------------------------------------------------------
extern "C" void kernel_launch(void* const* d_in, const int* in_sizes, int n_in,
                              void* d_out, int out_size, void* d_ws, size_t ws_size,
                              hipStream_t stream) {
  const float* boxes = (const float*)d_in[0];  // (B, N, 7)
  const float* cls = (const float*)d_in[1];    // (B, N, 3)
  float* out = (float*)d_out;                  // rois | scores | labels, flat f32

  char* w = (char*)d_ws;
  float* scores = (float*)w;    w += (size_t)BB * NN * 4;
  int* labels = (int*)w;        w += (size_t)BB * NN * 4;
  int* top_idx = (int*)w;       w += (size_t)BB * PRE * 4;
  float* top_score = (float*)w; w += (size_t)BB * PRE * 4;
  float* bx1 = (float*)w;       w += (size_t)BB * PRE * 4;
  float* bx2 = (float*)w;       w += (size_t)BB * PRE * 4;
  float* by1 = (float*)w;       w += (size_t)BB * PRE * 4;
  float* by2 = (float*)w;       w += (size_t)BB * PRE * 4;
  float* bar = (float*)w;       w += (size_t)BB * PRE * 4;
  u64* mask = (u64*)w;          w += (size_t)BB * PRE * NW * 8;
  u64* keepw = (u64*)w;         w += (size_t)BB * 64 * 8;
  int* st_info = (int*)w;       w += (size_t)BB * 2 * 4;
  u32* bhist = (u32*)w;         w += (size_t)BB * 16 * NBIN * 4;
  u64* ceq = (u64*)w;           w += (size_t)BB * CEQ * 8;

  // hot path
  prep_kernel<<<dim3(16, BB), 256, 0, stream>>>(cls, scores, labels, bhist);
  selsort_kernel<<<BB, 1024, 0, stream>>>(scores, boxes, bhist, ceq,
                                          top_idx, top_score, bx1, bx2, by1, by2, bar);
  mask_prefix_kernel<<<dim3(PREF_CH, PREF_CH, BB), 64, 0, stream>>>(
      bx1, bx2, by1, by2, bar, mask);
  nms_kernel_t<false><<<BB, 256, 0, stream>>>(mask, keepw, st_info);
  // fallback chain (exits immediately when prefix found >= POST keepers)
  select_kernel_t<PRE, true><<<BB, 1024, 0, stream>>>(
      scores, boxes, st_info, top_idx, top_score, bx1, bx2, by1, by2, bar);
  mask_full_kernel<<<dim3(16, BB), 256, 0, stream>>>(
      bx1, bx2, by1, by2, bar, mask, st_info);
  nms_kernel_t<true><<<BB, 256, 0, stream>>>(mask, keepw, st_info);
  // output
  output_kernel<<<BB, 1024, 0, stream>>>(keepw, top_idx, top_score, labels, boxes, out);
}

// Round 13
// 115.281 us; speedup vs baseline: 1.2896x; 1.0001x over previous
//
#include <hip/hip_runtime.h>
#include <cstdint>
#include <cstddef>

#define BB 4
#define NN 32768
#define PRE 4096
#define POST 512
#define NW 64        // u64 words per full mask row = PRE/64
#define PSEL 1024    // prefix selection size (hot path)
#define PREF_CH 16   // PSEL/64 chunks
#define NBIN 4096    // 12-bit bins (enc >> 20)
#define CEQ 32768    // eq-bin candidate capacity (cannot overflow)

typedef unsigned long long u64;
typedef unsigned int u32;
typedef float f4u __attribute__((ext_vector_type(4), aligned(4)));  // 4B-aligned float4

// LDS bank-conflict swizzle for the fallback's u64 sort buffer
#define SW(i) ((i) ^ (((i) >> 4) & 15))

__device__ __forceinline__ u32 enc_f32(float f) {
  u32 u = __float_as_uint(f);
  u32 m = (u32)((int)u >> 31) | 0x80000000u;  // neg -> 0xFFFFFFFF, pos -> 0x80000000
  return u ^ m;                                // ascending u <=> ascending f
}
// exact inverse of enc_f32 (bijection, bit-exact; verified R10/R12 replay)
__device__ __forceinline__ float dec_f32(u32 e) {
  u32 u = (e & 0x80000000u) ? (e ^ 0x80000000u) : ~e;
  return __uint_as_float(u);
}

// ======== kernel 1: scores/labels from cls + per-block 4096-bin hist ========
// R13: per-WAVE privatized LDS histograms (4x4096) to cut same-address
// atomic serialization from score clustering; merged on global writeout.
__global__ __launch_bounds__(256) void prep_kernel(
    const float* __restrict__ cls, float* __restrict__ scores,
    int* __restrict__ labels, u32* __restrict__ bhist) {
  int blk = blockIdx.x, b = blockIdx.y;
  int tid = threadIdx.x, wv = tid >> 6;
  __shared__ u32 lhist[4][NBIN];
  for (int i = tid; i < 4 * NBIN; i += 256) ((u32*)lhist)[i] = 0;
  __syncthreads();

  const int E = blk * 2048 + tid * 8;  // batch-relative element
  const float4* cp4 = (const float4*)(cls + ((size_t)b * NN + E) * 3);
  float4 v0 = cp4[0], v1 = cp4[1], v2 = cp4[2], v3 = cp4[3], v4 = cp4[4], v5 = cp4[5];
  float fa[24] = {v0.x, v0.y, v0.z, v0.w, v1.x, v1.y, v1.z, v1.w,
                  v2.x, v2.y, v2.z, v2.w, v3.x, v3.y, v3.z, v3.w,
                  v4.x, v4.y, v4.z, v4.w, v5.x, v5.y, v5.z, v5.w};
  float sc8[8];
  int lb8[8];
#pragma unroll
  for (int k = 0; k < 8; ++k) {
    float c0 = fa[3 * k], c1 = fa[3 * k + 1], c2 = fa[3 * k + 2];
    float m = c0; int l = 0;
    if (c1 > m) { m = c1; l = 1; }
    if (c2 > m) { m = c2; l = 2; }
    sc8[k] = m;
    lb8[k] = l;
    atomicAdd(&lhist[wv][enc_f32(m) >> 20], 1u);
  }
  float4* so = (float4*)(scores + (size_t)b * NN + E);
  so[0] = make_float4(sc8[0], sc8[1], sc8[2], sc8[3]);
  so[1] = make_float4(sc8[4], sc8[5], sc8[6], sc8[7]);
  int4* lo = (int4*)(labels + (size_t)b * NN + E);
  lo[0] = make_int4(lb8[0], lb8[1], lb8[2], lb8[3]);
  lo[1] = make_int4(lb8[4], lb8[5], lb8[6], lb8[7]);
  __syncthreads();
  u32* row = bhist + (size_t)(b * 16 + blk) * NBIN;
  for (int i = tid; i < NBIN; i += 256)
    row[i] = lhist[0][i] + lhist[1][i] + lhist[2][i] + lhist[3][i];
}

// ======== hybrid bitonic sort of 1024 u64, 1 elem/thread (proven r6..r12) ===
__device__ __forceinline__ u64 hybrid_sort1024(u64 key, u64* sortbuf, int tid) {
#pragma unroll
  for (int k2 = 2; k2 <= 64; k2 <<= 1) {
    for (int j = k2 >> 1; j > 0; j >>= 1) {
      u64 o = __shfl_xor(key, j, 64);
      bool take_max = (((tid & k2) == 0) == ((tid & j) == 0));
      key = ((key > o) == take_max) ? key : o;
    }
  }
  for (int k2 = 128; k2 <= PSEL; k2 <<= 1) {
    for (int j = k2 >> 1; j >= 64; j >>= 1) {
      __syncthreads();
      sortbuf[tid] = key;
      __syncthreads();
      u64 o = sortbuf[tid ^ j];
      bool take_max = (((tid & k2) == 0) == ((tid & j) == 0));
      key = ((key > o) == take_max) ? key : o;
    }
    for (int j = 32; j > 0; j >>= 1) {
      u64 o = __shfl_xor(key, j, 64);
      bool take_max = (((tid & k2) == 0) == ((tid & j) == 0));
      key = ((key > o) == take_max) ? key : o;
    }
  }
  return key;
}

// ======== kernel 2: fused pivot + compact + sort (grid BB x 1024) ===========
// R13: pivot suffix-scan via wave shfl_down + 16-wide cross-wave scan
// (2 barriers instead of 20); same crossing semantics as R12.
__global__ __launch_bounds__(1024) void selsort_kernel(
    const float* __restrict__ scores, const float* __restrict__ boxes,
    const u32* __restrict__ bhist, u64* __restrict__ ceq,
    int* __restrict__ top_idx, float* __restrict__ top_score,
    float* __restrict__ bx1, float* __restrict__ bx2,
    float* __restrict__ by1, float* __restrict__ by2, float* __restrict__ bar) {
  int b = blockIdx.x;
  int tid = threadIdx.x, lane = tid & 63, wv = tid >> 6;
  __shared__ u64 sortbuf[PSEL];   // sort scratch
  __shared__ u64 ebuf[PSEL];      // assembled final candidate keys
  __shared__ u32 wsums[16];
  __shared__ int sh_pb, sh_need;
  __shared__ u32 sh_cg, sh_cm;

  // --- pivot: sum the 16 block-hists (4 bins/thread, ascending with tid) ---
  u32 s0 = 0, s1 = 0, s2 = 0, s3 = 0;
#pragma unroll
  for (int k = 0; k < 16; ++k) {
    const u32* hb = bhist + (size_t)(b * 16 + k) * NBIN + tid * 4;
    s0 += hb[0]; s1 += hb[1]; s2 += hb[2]; s3 += hb[3];
  }
  const u32 T = s0 + s1 + s2 + s3;
  // wave-level inclusive suffix scan (lanes >= lane hold bins >= mine)
  u32 v = T;
#pragma unroll
  for (int off = 1; off < 64; off <<= 1) {
    u32 t = __shfl_down(v, off, 64);
    if (lane + off < 64) v += t;
  }
  if (lane == 0) wsums[wv] = v;  // wave total
  __syncthreads();
  if (tid < 16) {  // exclusive suffix over wave totals (waves > tid)
    u32 wt = wsums[tid];
    u32 v2 = wt;
#pragma unroll
    for (int off = 1; off < 16; off <<= 1) {
      u32 t = __shfl_down(v2, off, 64);
      if (tid + off < 16) v2 += t;
    }
    wsums[tid] = v2 - wt;
  }
  if (tid == 0) { sh_cg = 0; sh_cm = 0; }
  __syncthreads();
  {
    u32 suffix_incl = v + wsums[wv];       // == old ssum[tid]
    u32 cum = suffix_incl - T;             // == old ssum[tid+1] (bins above mine)
    u32 incl;
    incl = cum + s3; if (incl >= (u32)PSEL && cum < (u32)PSEL) { sh_pb = tid * 4 + 3; sh_need = PSEL - (int)cum; } cum = incl;
    incl = cum + s2; if (incl >= (u32)PSEL && cum < (u32)PSEL) { sh_pb = tid * 4 + 2; sh_need = PSEL - (int)cum; } cum = incl;
    incl = cum + s1; if (incl >= (u32)PSEL && cum < (u32)PSEL) { sh_pb = tid * 4 + 1; sh_need = PSEL - (int)cum; } cum = incl;
    incl = cum + s0; if (incl >= (u32)PSEL && cum < (u32)PSEL) { sh_pb = tid * 4 + 0; sh_need = PSEL - (int)cum; } cum = incl;
  }
  __syncthreads();
  const u32 pb = (u32)sh_pb;

  // --- compact: 32 scores/thread; wave shfl-scan + 2 LDS atomics per wave ---
  u32 encs[32];
  {
    const float4* sc4 = (const float4*)(scores + (size_t)b * NN + tid * 32);
#pragma unroll
    for (int k = 0; k < 8; ++k) {
      float4 vv = sc4[k];
      encs[k * 4 + 0] = enc_f32(vv.x);
      encs[k * 4 + 1] = enc_f32(vv.y);
      encs[k * 4 + 2] = enc_f32(vv.z);
      encs[k * 4 + 3] = enc_f32(vv.w);
    }
  }
  u32 gtl = 0, eql = 0;
#pragma unroll
  for (int k = 0; k < 32; ++k) {
    u32 bin = encs[k] >> 20;
    gtl += (bin > pb);
    eql += (bin == pb);
  }
  u64 pack = ((u64)gtl << 32) | eql;
#pragma unroll
  for (int off = 1; off < 64; off <<= 1) {
    u64 t = __shfl_up(pack, off, 64);
    if (lane >= off) pack += t;
  }
  u64 tot = __shfl(pack, 63, 64);
  u32 bg = 0, be = 0;
  if (lane == 63) {
    bg = atomicAdd(&sh_cg, (u32)(tot >> 32));
    be = atomicAdd(&sh_cm, (u32)(tot & 0xFFFFFFFFu));
  }
  bg = (u32)__shfl((int)bg, 63, 64);
  be = (u32)__shfl((int)be, 63, 64);
  int pg = (int)(bg + (u32)(pack >> 32) - gtl);
  int pe = (int)(be + (u32)(pack & 0xFFFFFFFFu) - eql);
#pragma unroll
  for (int k = 0; k < 32; ++k) {
    u32 bin = encs[k] >> 20;
    u64 key = ((u64)encs[k] << 32) | (u32)(~(u32)(tid * 32 + k));
    if (bin > pb) ebuf[pg++] = key;
    else if (bin == pb) ceq[(size_t)b * CEQ + (pe++)] = key;
  }
  __syncthreads();

  const int g = (int)sh_cg;     // count in bins > pb ( < PSEL by crossing )
  const int m = (int)sh_cm;     // count in pivot bin ( >= need )
  const int need = sh_need;     // g + need == PSEL

  if (m <= PSEL) {  // common case: sort the pivot bin, take its top-need
    u64 ek = (tid < m) ? ceq[(size_t)b * CEQ + tid] : 0ull;
    ek = hybrid_sort1024(ek, sortbuf, tid);   // ek = tid-th largest eq key
    if (tid < need) ebuf[g + tid] = ek;
  } else {          // rare: rank by scan (exact for any m)
    const int qmax = (m + 1023) >> 10;
    for (int q = 0; q < qmax; ++q) {
      int i = q * 1024 + tid;
      u64 kk = (i < m) ? ceq[(size_t)b * CEQ + i] : 0ull;
      u32 rr = 0;
      for (int base2 = 0; base2 < m; base2 += 1024) {
        int cn = min(1024, m - base2);
        __syncthreads();
        if (tid < cn) sortbuf[tid] = ceq[(size_t)b * CEQ + base2 + tid];
        __syncthreads();
        for (int j = 0; j < cn; ++j) rr += (sortbuf[j] > kk);
      }
      if (i < m && rr < (u32)need) ebuf[g + rr] = kk;  // ranks unique
    }
  }
  __syncthreads();

  u64 key = ebuf[tid];
  key = hybrid_sort1024(key, sortbuf, tid);

  // --- epilogue: score decoded from key; box via two 4B-aligned float4 ---
  {
#pragma clang fp contract(off)
    u32 ue = (u32)(key >> 32);
    int e = (int)(~(u32)key);
    top_idx[b * PRE + tid] = e;
    top_score[b * PRE + tid] = dec_f32(ue);
    const float* bx = boxes + ((size_t)b * NN + e) * 7;
    f4u p0 = *(const f4u*)(bx);       // x, y, z, dx
    f4u p1 = *(const f4u*)(bx + 3);   // dx, dy, dz, heading
    float x = p0.x, y = p0.y, dx = p0.w, dy = p1.y;
    float hx = dx * 0.5f, hy = dy * 0.5f;
    bx1[b * PRE + tid] = x - hx;
    bx2[b * PRE + tid] = x + hx;
    by1[b * PRE + tid] = y - hy;
    by2[b * PRE + tid] = y + hy;
    bar[b * PRE + tid] = dx * dy;
  }
}

// ======== cold fallback: round-4 top-PRE select (gated) =====================
template<int SELN, bool GATED>
__global__ __launch_bounds__(1024) void select_kernel_t(
    const float* __restrict__ scores, const float* __restrict__ boxes,
    const int* __restrict__ st_info,
    int* __restrict__ top_idx, float* __restrict__ top_score,
    float* __restrict__ bx1, float* __restrict__ bx2,
    float* __restrict__ by1, float* __restrict__ by2, float* __restrict__ bar) {
  int b = blockIdx.x;
  if (GATED && st_info[b * 2 + 0] >= POST) return;  // fallback not needed
  int tid = threadIdx.x;
  int wv = tid >> 6;
  const float* sc = scores + (size_t)b * NN;

  __shared__ u32 hist16[16][256];   // per-wave privatized histograms
  __shared__ u32 sA[256], sB[256];  // suffix-scan ping-pong
  __shared__ u32 scanbuf[1024];
  __shared__ u64 sortbuf[SELN];
  __shared__ u32 sh_prefix;
  __shared__ int sh_rem;

  const int e0 = tid * 32;
  u32 encs[32];
  {
    const float4* sc4 = (const float4*)(sc + e0);
#pragma unroll
    for (int k = 0; k < 8; ++k) {
      float4 v = sc4[k];
      encs[k * 4 + 0] = enc_f32(v.x);
      encs[k * 4 + 1] = enc_f32(v.y);
      encs[k * 4 + 2] = enc_f32(v.z);
      encs[k * 4 + 3] = enc_f32(v.w);
    }
  }

  u32 prefix = 0, known = 0;
  int remaining = SELN;
  for (int shift = 24; shift >= 0; shift -= 8) {
    for (int k = tid; k < 16 * 256; k += 1024) ((u32*)hist16)[k] = 0;
    __syncthreads();
#pragma unroll
    for (int k = 0; k < 32; ++k) {
      u32 u = encs[k];
      if ((u & known) == prefix) atomicAdd(&hist16[wv][(u >> shift) & 255u], 1u);
    }
    __syncthreads();
    if (tid < 256) {
      u32 t = 0;
#pragma unroll
      for (int w2 = 0; w2 < 16; ++w2) t += hist16[w2][tid];
      sA[tid] = t;
    }
    __syncthreads();
    u32* src = sA; u32* dst = sB;
    for (int off = 1; off < 256; off <<= 1) {
      if (tid < 256) dst[tid] = src[tid] + ((tid + off < 256) ? src[tid + off] : 0u);
      __syncthreads();
      u32* tp = src; src = dst; dst = tp;
    }
    if (tid < 256) {
      u32 sv = src[tid];
      u32 svn = (tid < 255) ? src[tid + 1] : 0u;
      if (sv >= (u32)remaining && svn < (u32)remaining) {
        sh_prefix = prefix | ((u32)tid << shift);
        sh_rem = remaining - (int)svn;
      }
    }
    __syncthreads();
    prefix = sh_prefix;
    remaining = sh_rem;
    known |= (0xFFu << shift);
    __syncthreads();
  }
  const u32 pivot = prefix;

  int gtc = 0, eqc = 0;
#pragma unroll
  for (int k = 0; k < 32; ++k) {
    gtc += (encs[k] > pivot);
    eqc += (encs[k] == pivot);
  }
  scanbuf[tid] = ((u32)gtc << 16) | (u32)eqc;
  __syncthreads();
  for (int off = 1; off < 1024; off <<= 1) {
    u32 v = scanbuf[tid];
    u32 add = (tid >= off) ? scanbuf[tid - off] : 0u;
    __syncthreads();
    scanbuf[tid] = v + add;
    __syncthreads();
  }
  u32 incl = scanbuf[tid];
  u32 totpk = scanbuf[1023];
  const int cnt_gt = (int)(totpk >> 16);
  int gt_base = (int)(incl >> 16) - gtc;
  int eq_base = (int)(incl & 0xFFFFu) - eqc;
  int gs = 0, es = 0;
#pragma unroll
  for (int k = 0; k < 32; ++k) {
    u32 u = encs[k];
    int e = e0 + k;
    u64 key = ((u64)u << 32) | (u32)(~(u32)e);
    if (u > pivot) {
      sortbuf[SW(gt_base + gs)] = key; gs++;
    } else if (u == pivot) {
      int g = eq_base + (es++);
      if (g < remaining) sortbuf[SW(cnt_gt + g)] = key;
    }
  }
  __syncthreads();

  for (int k = 2; k <= SELN; k <<= 1) {
    for (int j = k >> 1; j > 0; j >>= 1) {
      for (int p = tid; p < SELN / 2; p += 1024) {
        int low = p & (j - 1);
        int i = ((p ^ low) << 1) | low;
        int ixj = i + j;
        u64 a = sortbuf[SW(i)], c = sortbuf[SW(ixj)];
        bool desc = ((i & k) == 0);
        if (desc ? (a < c) : (a > c)) { sortbuf[SW(i)] = c; sortbuf[SW(ixj)] = a; }
      }
      __syncthreads();
    }
  }
  {
#pragma clang fp contract(off)
    for (int s = tid; s < SELN; s += 1024) {
      u64 key = sortbuf[SW(s)];
      int e = (int)(~(u32)(key & 0xFFFFFFFFull));
      top_idx[b * PRE + s] = e;
      top_score[b * PRE + s] = sc[e];
      const float* bx = boxes + ((size_t)b * NN + e) * 7;
      float x = bx[0], y = bx[1], dx = bx[3], dy = bx[4];
      float hx = dx * 0.5f, hy = dy * 0.5f;
      bx1[b * PRE + s] = x - hx;
      bx2[b * PRE + s] = x + hx;
      by1[b * PRE + s] = y - hy;
      by2[b * PRE + s] = y + hy;
      bar[b * PRE + s] = dx * dy;
    }
  }
}

// ---------------- suppression bitmask (iou > 0.7, j > i) --------------------
__device__ __forceinline__ void mask_tile(
    const float* __restrict__ bx1, const float* __restrict__ bx2,
    const float* __restrict__ by1, const float* __restrict__ by2,
    const float* __restrict__ bar, u64* __restrict__ mask,
    int b, int rb, int cb, int t) {
#pragma clang fp contract(off)
  int i = rb * 64 + t;
  int j0 = cb * 64 + t;
  float cx1 = bx1[b * PRE + j0], cx2 = bx2[b * PRE + j0];
  float cy1 = by1[b * PRE + j0], cy2 = by2[b * PRE + j0];
  float car = bar[b * PRE + j0];
  float ix1 = bx1[b * PRE + i], ix2 = bx2[b * PRE + i];
  float iy1 = by1[b * PRE + i], iy2 = by2[b * PRE + i];
  float ia = bar[b * PRE + i];
  u64 bits = 0ull;
  int jbase = cb * 64;
  for (int jj = 0; jj < 64; ++jj) {
    float jx1 = __shfl(cx1, jj, 64);
    float jx2 = __shfl(cx2, jj, 64);
    float jy1 = __shfl(cy1, jj, 64);
    float jy2 = __shfl(cy2, jj, 64);
    float jar = __shfl(car, jj, 64);
    if (jbase + jj > i) {
      float iw = fminf(ix2, jx2) - fmaxf(ix1, jx1);
      iw = fmaxf(iw, 0.0f);
      float ih = fminf(iy2, jy2) - fmaxf(iy1, jy1);
      ih = fmaxf(ih, 0.0f);
      float inter = iw * ih;
      float uni = ia + jar - inter;
      float iou = inter / fmaxf(uni, 1e-6f);
      if (iou > 0.7f) bits |= (1ull << jj);
    }
  }
  mask[((size_t)b * PRE + i) * NW + cb] = bits;
}

__global__ void mask_prefix_kernel(const float* __restrict__ bx1, const float* __restrict__ bx2,
                                   const float* __restrict__ by1, const float* __restrict__ by2,
                                   const float* __restrict__ bar, u64* __restrict__ mask) {
  int cb = blockIdx.x, rb = blockIdx.y, b = blockIdx.z;
  if (cb < rb) return;
  mask_tile(bx1, bx2, by1, by2, bar, mask, b, rb, cb, threadIdx.x);
}

// gated fallback: grid-strided (small dispatch when gated; never runs here)
__global__ __launch_bounds__(256) void mask_full_kernel(
    const float* __restrict__ bx1, const float* __restrict__ bx2,
    const float* __restrict__ by1, const float* __restrict__ by2,
    const float* __restrict__ bar, u64* __restrict__ mask,
    const int* __restrict__ st_info) {
  int b = blockIdx.y;
  if (st_info[b * 2 + 0] >= POST) return;
  int cb = blockIdx.x * 4 + (threadIdx.x >> 6);
  int t = threadIdx.x & 63;
  for (int rb = 0; rb <= cb; ++rb)
    mask_tile(bx1, bx2, by1, by2, bar, mask, b, rb, cb, t);
}

// ---------------- chunked greedy NMS, 4 waves per batch ---------------------
// Prefix variant: only mask words 0..15 exist (PSEL=1024); wave = 4 row-groups
// x 16 words (lane = g*16 + w), 4 loads/lane = 16 rows/wave, shfl_xor combine.
template<bool FULL>
__global__ __launch_bounds__(256) void nms_kernel_t(
    const u64* __restrict__ mask, u64* __restrict__ keep_words,
    int* __restrict__ st_info) {
  int b = blockIdx.x;
  if (FULL && st_info[b * 2 + 0] >= POST) return;  // hot path already done
  int tid = threadIdx.x;
  int lane = tid & 63;
  int wv = tid >> 6;

  const u64* base = mask + (size_t)b * PRE * NW;
  u64 rem = 0ull, keepw = 0ull;
  int kept = 0;
  int c = 0;

  if constexpr (!FULL) {
    __shared__ u64 part[2][4][16];
    const int g16 = lane >> 4;   // row subgroup 0..3
    const int w = lane & 15;     // word 0..15
    while (c < PREF_CH) {
      u64 remc = __shfl(rem, c, 64);  // rem replicated every 16 lanes
      // 4 loads/lane: rows wv*16 + k*4 + g16, word w
      const u64* rowb = base + ((size_t)(c * 64 + wv * 16)) * NW + w;
      u64 m0 = rowb[(size_t)(0 + g16) * NW];
      u64 m1 = rowb[(size_t)(4 + g16) * NW];
      u64 m2 = rowb[(size_t)(8 + g16) * NW];
      u64 m3 = rowb[(size_t)(12 + g16) * NW];
      // diagonal word of row (c*64+lane): within-chunk suppression candidates
      u64 dg = base[((size_t)(c * 64 + lane)) * NW + c];
      u64 nz = __ballot(dg != 0ull);
      while (nz) {
        int i2 = __builtin_ctzll(nz);
        nz &= nz - 1ull;
        u64 di = __shfl(dg, i2, 64);
        if (!((remc >> i2) & 1ull)) remc |= di;
      }
      u64 K = ~remc;
      if (lane == c) keepw = K;
      kept += __popcll(K);

      u64 acc = 0ull;
      if ((K >> (wv * 16 + 0 + g16)) & 1ull) acc |= m0;
      if ((K >> (wv * 16 + 4 + g16)) & 1ull) acc |= m1;
      if ((K >> (wv * 16 + 8 + g16)) & 1ull) acc |= m2;
      if ((K >> (wv * 16 + 12 + g16)) & 1ull) acc |= m3;
      acc |= __shfl_xor(acc, 16, 64);
      acc |= __shfl_xor(acc, 32, 64);   // all lanes: OR over wave's 16 rows for word (lane&15)
      if (g16 == 0) part[c & 1][wv][w] = acc;
      __syncthreads();
      rem |= part[c & 1][0][w] | part[c & 1][1][w] |
             part[c & 1][2][w] | part[c & 1][3][w];
      ++c;
      if (kept >= POST) break;  // uniform
    }
  } else {
    __shared__ u64 part[2][4][64];
    while (c < NW) {
      u64 remc = __shfl(rem, c, 64);
      const u64* rowp = base + ((size_t)(c * 64 + wv * 16)) * NW + lane;
      u64 m[16];
#pragma unroll
      for (int k = 0; k < 16; ++k) m[k] = rowp[(size_t)k * NW];
      u64 dg = base[((size_t)(c * 64 + lane)) * NW + c];
      u64 nz = __ballot(dg != 0ull);
      while (nz) {
        int i2 = __builtin_ctzll(nz);
        nz &= nz - 1ull;
        u64 di = __shfl(dg, i2, 64);
        if (!((remc >> i2) & 1ull)) remc |= di;
      }
      u64 K = ~remc;
      if (lane == c) keepw = K;
      kept += __popcll(K);

      u32 kb = (u32)((K >> (wv * 16)) & 0xFFFFull);
      u64 acc = 0ull;
#pragma unroll
      for (int k = 0; k < 16; ++k)
        if ((kb >> k) & 1u) acc |= m[k];
      part[c & 1][wv][lane] = acc;
      __syncthreads();
      rem |= part[c & 1][0][lane] | part[c & 1][1][lane] |
             part[c & 1][2][lane] | part[c & 1][3][lane];
      ++c;
      if (kept >= POST) break;  // uniform
    }
  }

  if (wv == 0) {
    keep_words[b * 64 + lane] = keepw;  // unprocessed chunks -> 0
    if (!FULL && lane == 0) st_info[b * 2 + 0] = kept;
  }
}

// ---------------- emit first POST kept entries ------------------------------
__global__ __launch_bounds__(1024) void output_kernel(
    const u64* __restrict__ keep_words, const int* __restrict__ top_idx,
    const float* __restrict__ top_score, const int* __restrict__ labels,
    const float* __restrict__ boxes, float* __restrict__ out) {
  int b = blockIdx.x, tid = threadIdx.x;
  __shared__ u32 scanbuf[1024];
  __shared__ int sh_total;

  u64 w = keep_words[b * 64 + (tid >> 4)];
  u32 my4 = (u32)((w >> ((tid & 15) * 4)) & 0xFull);  // 4 consecutive i per thread
  int cnt = __popc(my4);
  scanbuf[tid] = (u32)cnt;
  __syncthreads();
  for (int off = 1; off < 1024; off <<= 1) {
    u32 v = scanbuf[tid];
    u32 add = (tid >= off) ? scanbuf[tid - off] : 0u;
    __syncthreads();
    scanbuf[tid] = v + add;
    __syncthreads();
  }
  int base = (int)scanbuf[tid] - cnt;
  if (tid == 1023) sh_total = (int)scanbuf[1023];
  __syncthreads();
  int total = sh_total;

  float* rois = out;                 // BB*POST*7
  float* rsc = out + BB * POST * 7;  // BB*POST
  float* rlb = rsc + BB * POST;      // BB*POST (labels as f32)

  int r = 0;
  for (int k = 0; k < 4; ++k) {
    if ((my4 >> k) & 1u) {
      int rank = base + (r++);
      if (rank < POST) {
        int i = tid * 4 + k;
        int idx = top_idx[b * PRE + i];
        const float* bx = boxes + ((size_t)b * NN + idx) * 7;
        float* ro = rois + ((size_t)b * POST + rank) * 7;
        for (int c = 0; c < 7; ++c) ro[c] = bx[c];
        rsc[b * POST + rank] = top_score[b * PRE + i];
        rlb[b * POST + rank] = (float)(labels[b * NN + idx] + 1);
      }
    }
  }
  // invalid slots: rois = 0, score = 0, label = 0 + 1
  for (int s = tid; s < POST; s += 1024) {
    if (s >= total) {
      float* ro = rois + ((size_t)b * POST + s) * 7;
      for (int c = 0; c < 7; ++c) ro[c] = 0.0f;
      rsc[b * POST + s] = 0.0f;
      rlb[b * POST + s] = 1.0f;
    }
  }
}

// ---------------------------------------------------------------------------
extern "C" void kernel_launch(void* const* d_in, const int* in_sizes, int n_in,
                              void* d_out, int out_size, void* d_ws, size_t ws_size,
                              hipStream_t stream) {
  const float* boxes = (const float*)d_in[0];  // (B, N, 7)
  const float* cls = (const float*)d_in[1];    // (B, N, 3)
  float* out = (float*)d_out;                  // rois | scores | labels, flat f32

  char* w = (char*)d_ws;
  float* scores = (float*)w;    w += (size_t)BB * NN * 4;
  int* labels = (int*)w;        w += (size_t)BB * NN * 4;
  int* top_idx = (int*)w;       w += (size_t)BB * PRE * 4;
  float* top_score = (float*)w; w += (size_t)BB * PRE * 4;
  float* bx1 = (float*)w;       w += (size_t)BB * PRE * 4;
  float* bx2 = (float*)w;       w += (size_t)BB * PRE * 4;
  float* by1 = (float*)w;       w += (size_t)BB * PRE * 4;
  float* by2 = (float*)w;       w += (size_t)BB * PRE * 4;
  float* bar = (float*)w;       w += (size_t)BB * PRE * 4;
  u64* mask = (u64*)w;          w += (size_t)BB * PRE * NW * 8;
  u64* keepw = (u64*)w;         w += (size_t)BB * 64 * 8;
  int* st_info = (int*)w;       w += (size_t)BB * 2 * 4;
  u32* bhist = (u32*)w;         w += (size_t)BB * 16 * NBIN * 4;
  u64* ceq = (u64*)w;           w += (size_t)BB * CEQ * 8;

  // hot path
  prep_kernel<<<dim3(16, BB), 256, 0, stream>>>(cls, scores, labels, bhist);
  selsort_kernel<<<BB, 1024, 0, stream>>>(scores, boxes, bhist, ceq,
                                          top_idx, top_score, bx1, bx2, by1, by2, bar);
  mask_prefix_kernel<<<dim3(PREF_CH, PREF_CH, BB), 64, 0, stream>>>(
      bx1, bx2, by1, by2, bar, mask);
  nms_kernel_t<false><<<BB, 256, 0, stream>>>(mask, keepw, st_info);
  // fallback chain (exits immediately when prefix found >= POST keepers)
  select_kernel_t<PRE, true><<<BB, 1024, 0, stream>>>(
      scores, boxes, st_info, top_idx, top_score, bx1, bx2, by1, by2, bar);
  mask_full_kernel<<<dim3(16, BB), 256, 0, stream>>>(
      bx1, bx2, by1, by2, bar, mask, st_info);
  nms_kernel_t<true><<<BB, 256, 0, stream>>>(mask, keepw, st_info);
  // output
  output_kernel<<<BB, 1024, 0, stream>>>(keepw, top_idx, top_score, labels, boxes, out);
}